// Round 14
// baseline (630.775 us; speedup 1.0000x reference)
//
#include <hip/hip_runtime.h>
#include <hip/hip_bf16.h>
#include <math.h>

typedef __bf16 bf16;
typedef __bf16 bf16x4 __attribute__((ext_vector_type(4)));
typedef __bf16 bf16x8 __attribute__((ext_vector_type(8)));
typedef float  f32x4  __attribute__((ext_vector_type(4)));
typedef short  s16x4  __attribute__((ext_vector_type(4)));

#define T_TOK 4096
#define DIM   1024
#define NHEAD 16
#define SEQ   2048
#define NEXP  4
#define CAP   2048
#define MLPH  4096
#define MOEH  256

__device__ __forceinline__ float gelu_exact(float v) {
    return 0.5f * v * (1.f + erff(v * 0.70710678118654752f));
}

struct HL { bf16 h, l; };
__device__ __forceinline__ HL split2(float v) {
    HL r; r.h = (bf16)v; r.l = (bf16)(v - (float)r.h); return r;
}

__device__ __forceinline__ float fast_exp2(float x) {
#if __has_builtin(__builtin_amdgcn_exp2f)
    return __builtin_amdgcn_exp2f(x);
#else
    return exp2f(x);
#endif
}

// K=16 bf16 MFMA: B-fragment layout (k = l4*4+r, n = l16) matches the QK^T C-layout -> direct P feed
__device__ __forceinline__ f32x4 mfma16(bf16x4 a, bf16x4 b, f32x4 c) {
    return __builtin_amdgcn_mfma_f32_16x16x16bf16_1k(
        __builtin_bit_cast(s16x4, a), __builtin_bit_cast(s16x4, b), c, 0, 0, 0);
}

// async global->LDS, 16B per lane; LDS dest = wave-uniform base + lane*16
__device__ __forceinline__ void gload16(const bf16* gptr, bf16* lptr) {
    __builtin_amdgcn_global_load_lds(
        (const __attribute__((address_space(1))) unsigned int*)gptr,
        (__attribute__((address_space(3))) unsigned int*)lptr,
        16, 0, 0);
}

// swizzled fragment read: logical (row, 16B-chunk cc) stored at chunk cc^(row&7)
// (staging pre-swizzles the GLOBAL source chunk by r8, LDS dest stays linear -> both-sides swizzle)
__device__ __forceinline__ bf16x8 sw_frag(const bf16* arr, int row, int cc) {
    return *(const bf16x8*)&arr[row * 64 + ((cc ^ (row & 7)) * 8)];
}
// V fragment read (b64): quad q (4 keys) of row d stored at 8B slot q^(d&15)
// -> per 16-lane quarter the 16 slots are a bijection onto all 16 bank-pairs: conflict-free
__device__ __forceinline__ bf16x4 v_frag(const bf16* arr, int d, int q) {
    return *(const bf16x4*)&arr[d * 64 + ((q ^ (d & 15)) * 4)];
}

// T1: bijective XCD-aware tile remap — applied ONLY to gemm_bt (within-run counter proof:
// mlp2 FETCH 143->49 MB). qkv/proj measured FETCH +35% with it -> plain mapping there.
__device__ __forceinline__ void xcd_tile(int& bx, int& by) {
    int gx = gridDim.x;
    int nwg = gx * gridDim.y;
    int flat = blockIdx.y * gx + blockIdx.x;
    int q = nwg >> 3, r = nwg & 7;
    int xcd = flat & 7, loc = flat >> 3;
    int swz = (xcd < r ? xcd * (q + 1) : r * (q + 1) + (xcd - r) * q) + loc;
    bx = swz % gx; by = swz / gx;
}

// ---------------- LN1 -> hi/lo bf16 planes: one wave per token ----------------
__global__ __launch_bounds__(256)
void ln_split_kernel(const float* __restrict__ x, const float* __restrict__ g,
                     const float* __restrict__ b, bf16* __restrict__ oh, bf16* __restrict__ ol) {
    int wave = threadIdx.x >> 6, lane = threadIdx.x & 63;
    long t = (long)blockIdx.x * 4 + wave;
    const float* xr = x + t * DIM;
    float v[16];
    #pragma unroll
    for (int i = 0; i < 16; i++) v[i] = xr[i * 64 + lane];
    float s = 0.f, s2 = 0.f;
    #pragma unroll
    for (int i = 0; i < 16; i++) { s += v[i]; s2 += v[i] * v[i]; }
    #pragma unroll
    for (int m = 1; m < 64; m <<= 1) { s += __shfl_xor(s, m); s2 += __shfl_xor(s2, m); }
    float mu  = s * (1.f / DIM);
    float var = s2 * (1.f / DIM) - mu * mu;
    float rs  = 1.f / sqrtf(var + 1e-5f);
    #pragma unroll
    for (int i = 0; i < 16; i++) {
        int d = i * 64 + lane;
        HL sp = split2((v[i] - mu) * rs * g[d] + b[d]);
        oh[t * DIM + d] = sp.h; ol[t * DIM + d] = sp.l;
    }
}

// ---------------- elementwise fp32 -> hi/lo planes ----------------
__global__ __launch_bounds__(256)
void split_pair_kernel(const float* __restrict__ in, bf16* __restrict__ h, bf16* __restrict__ l) {
    long i0 = ((long)blockIdx.x * 256 + threadIdx.x) * 4;
    f32x4 v = *(const f32x4*)&in[i0];
    bf16x4 vh, vl;
    #pragma unroll
    for (int j = 0; j < 4; j++) { HL sp = split2(v[j]); vh[j] = sp.h; vl[j] = sp.l; }
    *(bf16x4*)&h[i0] = vh; *(bf16x4*)&l[i0] = vl;
}

// ---------------- transpose fp32 -> bf16 (32x32 tiles, batched in z) ----------------
__global__ __launch_bounds__(256)
void transpose_conv_kernel(const float* __restrict__ in, bf16* __restrict__ out, int R, int C) {
    __shared__ bf16 tile[32][33];
    long bo = (long)blockIdx.z * R * C;
    in += bo; out += bo;
    int c0 = blockIdx.x * 32, r0 = blockIdx.y * 32;
    int tx = threadIdx.x & 31, ty = threadIdx.x >> 5;
    #pragma unroll
    for (int i = 0; i < 32; i += 8)
        tile[ty + i][tx] = (bf16)in[(long)(r0 + ty + i) * C + c0 + tx];
    __syncthreads();
    #pragma unroll
    for (int i = 0; i < 32; i += 8)
        out[(long)(c0 + ty + i) * R + r0 + tx] = tile[tx][ty + i];
}

// ---------------- qkv split GEMM: glds staging (T2-swizzled); epilogue -> Q/K hi planes + hi-only Vt ----------------
// Q pre-scale folds log2(e): softmax downstream runs in exp2 domain.
// Attention path runs bf16-hi only (Q_lo/K_lo/V_lo dropped; each adds ~2^-9 rel err, >=10x under
// the 0.03125 absmax which is MLP-dominated).
// V stored transposed VtH[bh][d][s] with odd-d quad swap (s^4) so flash's conflict-free
// v_frag layout (quad q of row d at slot q^(d&15)) stages with linear global_load_lds.
__global__ __launch_bounds__(256)
void gemm_qkv(const bf16* __restrict__ Ah_g, const bf16* __restrict__ Al_g,
              const bf16* __restrict__ Bh_g, const bf16* __restrict__ Bl_g,
              bf16* __restrict__ Qh_g, bf16* __restrict__ Kh_g,
              bf16* __restrict__ VtH) {
    const int K = DIM;
    __shared__ alignas(16) bf16 Ah[8192], Al[8192], Bh[8192], Bl[8192];
    int tid = threadIdx.x;
    int wave = tid >> 6, lane = tid & 63;
    int l16 = lane & 15, l4 = lane >> 4;
    int wr = (wave >> 1) * 64, wc = (wave & 1) * 64;
    int row0 = blockIdx.y * 128, col0 = blockIdx.x * 128;
    int r8s = lane >> 3;                      // row within 8-row staging group (== row&7)
    int colb = ((lane & 7) ^ r8s) * 8;        // pre-swizzled global 16B chunk
    f32x4 acc[4][4] = {};
    for (int k0 = 0; k0 < K; k0 += 64) {
        #pragma unroll
        for (int p = 0; p < 4; p++) {
            int rl = p * 32 + wave * 8 + r8s;
            int lb = p * 2048 + wave * 512;
            gload16(&Ah_g[(long)(row0 + rl) * K + k0 + colb], &Ah[lb]);
            gload16(&Al_g[(long)(row0 + rl) * K + k0 + colb], &Al[lb]);
            gload16(&Bh_g[(long)(col0 + rl) * K + k0 + colb], &Bh[lb]);
            gload16(&Bl_g[(long)(col0 + rl) * K + k0 + colb], &Bl[lb]);
        }
        __syncthreads();
        #pragma unroll
        for (int ks = 0; ks < 2; ks++) {
            bf16x8 ah[4], al[4], bh[4], bl[4];
            #pragma unroll
            for (int i = 0; i < 4; i++) {
                ah[i] = sw_frag(Ah, wr + i*16 + l16, ks*4 + l4);
                al[i] = sw_frag(Al, wr + i*16 + l16, ks*4 + l4);
            }
            #pragma unroll
            for (int j = 0; j < 4; j++) {
                bh[j] = sw_frag(Bh, wc + j*16 + l16, ks*4 + l4);
                bl[j] = sw_frag(Bl, wc + j*16 + l16, ks*4 + l4);
            }
            #pragma unroll
            for (int i = 0; i < 4; i++)
                #pragma unroll
                for (int j = 0; j < 4; j++) {
                    acc[i][j] = __builtin_amdgcn_mfma_f32_16x16x32_bf16(ah[i], bh[j], acc[i][j], 0, 0, 0);
                    acc[i][j] = __builtin_amdgcn_mfma_f32_16x16x32_bf16(ah[i], bl[j], acc[i][j], 0, 0, 0);
                    acc[i][j] = __builtin_amdgcn_mfma_f32_16x16x32_bf16(al[i], bh[j], acc[i][j], 0, 0, 0);
                }
        }
        __syncthreads();
    }
    if (col0 < 2048) {   // Q/K columns -> hi planes [bh][s][64]; Q pre-scaled by log2(e)/8 (exp2-domain)
        bool isQ = (col0 < 1024);
        bf16* oh = isQ ? Qh_g : Kh_g;
        float qscale = isQ ? 0.18033688011112043f : 1.0f;
        #pragma unroll
        for (int i = 0; i < 4; i++)
            #pragma unroll
            for (int r = 0; r < 4; r++) {
                int t = row0 + wr + i * 16 + l4 * 4 + r;
                int bq = t >> 11, s = t & 2047;
                #pragma unroll
                for (int j = 0; j < 4; j++) {
                    int col = (col0 + wc + j * 16 + l16) & 1023;
                    int hh = col >> 6, dl = col & 63;
                    long o = ((long)(bq * NHEAD + hh) * SEQ + s) * 64 + dl;
                    oh[o] = (bf16)(acc[i][j][r] * qscale);
                }
            }
    } else {             // V columns -> hi-only transposed VtH[bh][d][s], r-packed b64 stores; odd-d quad swap
        #pragma unroll
        for (int i = 0; i < 4; i++) {
            int s0 = row0 + wr + i * 16 + l4 * 4;
            int b = s0 >> 11, sl = s0 & 2047;
            #pragma unroll
            for (int j = 0; j < 4; j++) {
                int d = col0 - 2048 + wc + j * 16 + l16;
                int h = d >> 6, dl = d & 63;
                long base = ((long)(b * NHEAD + h) * 64 + dl) * SEQ + (sl ^ ((dl & 1) << 2));
                bf16x4 vh;
                #pragma unroll
                for (int r = 0; r < 4; r++) vh[r] = (bf16)acc[i][j][r];
                *(bf16x4*)&VtH[base] = vh;
            }
        }
    }
}

// ---------------- flash attention: 8-wave blocks (128 q-rows), double-buffered K/V, counted vmcnt ----------------
// bf16-hi attention: S = K_hi x Q_hi (8 MFMAs/tile); PV = V_hi x P via K=16 MFMA with P fed
// straight from the QK accumulator (B-fragment k=l4*4+r == st layout; no shuffle, no LDS).
__global__ __launch_bounds__(512, 4)
void flash_attn(const bf16* __restrict__ Qh_g,
                const bf16* __restrict__ Kh_g,
                const bf16* __restrict__ VtH_g,
                bf16* __restrict__ aoh, bf16* __restrict__ aol) {
    __shared__ alignas(16) bf16 KhS[2][4096], VhS[2][4096];
    int tid = threadIdx.x;
    int wave = tid >> 6, lane = tid & 63;   // wave in [0,8)
    int l16 = lane & 15, l4 = lane >> 4;
    int bid = blockIdx.x;
    int bh = bid & 31;            // same-bh blocks share XCD (bid%8 == bh%8) -> K/V stay in that L2
    int b = bh >> 4, h = bh & 15;
    int q0 = (bid >> 5) * 128;

    // Q_hi fragments (pre-scaled by log2(e)/8 at producer) straight into registers
    bf16x8 qfh[2];
    {
        const bf16* qh = Qh_g + ((long)bh * SEQ + q0 + wave * 16 + l16) * 64;
        #pragma unroll
        for (int ks = 0; ks < 2; ks++)
            qfh[ks] = *(const bf16x8*)&qh[ks * 32 + l4 * 8];
    }
    int r8 = lane >> 3;
    int c8 = lane & 7;
    const bf16* kh_g = Kh_g + (long)bh * SEQ * 64;
    const bf16* vh_g = VtH_g + (long)bh * 64 * SEQ;

    float m_s = -1e30f, l_s = 0.f;
    f32x4 accO[4] = {};

    // stage one 64-key tile (2 gload16 per wave; wave w owns rows w*8..w*8+7) into buffer bsel
    auto stage = [&](int c0, int bsel) {
        int R0 = wave * 8;
        int row = R0 + r8;
        int ksw = (c8 ^ r8) * 8;                               // K: 16B chunk ^ (row&7)
        int vsw = (c8 ^ ((wave * 4 + (r8 >> 1)) & 7)) * 8;     // V: chunk ^ ((d>>1)&7); bit0 via global quad swap
        gload16(&kh_g[(long)(c0 + row) * 64 + ksw], &KhS[bsel][R0 * 64]);
        gload16(&vh_g[(long)row * SEQ + c0 + vsw], &VhS[bsel][R0 * 64]);
    };

    // one tile's compute on the given buffers
    auto compute = [&](const bf16* KhT, const bf16* VhT) {
        // S^T[key][q] = K_hi Q_hi^T for keys [0,64), q-cols [wave*16, +16)  (exp2 domain)
        f32x4 st[4] = {};
        __builtin_amdgcn_s_setprio(1);
        #pragma unroll
        for (int ks = 0; ks < 2; ks++) {
            #pragma unroll
            for (int i = 0; i < 4; i++) {
                bf16x8 akh = sw_frag(KhT, i * 16 + l16, ks * 4 + l4);
                st[i] = __builtin_amdgcn_mfma_f32_16x16x32_bf16(akh, qfh[ks], st[i], 0, 0, 0);
            }
        }
        __builtin_amdgcn_s_setprio(0);
        // online softmax over this lane's q-column (16 keys in-reg + 2 shuffles over l4)
        float mx = st[0][0];
        #pragma unroll
        for (int i = 0; i < 4; i++)
            #pragma unroll
            for (int r = 0; r < 4; r++) mx = fmaxf(mx, st[i][r]);
        mx = fmaxf(mx, __shfl_xor(mx, 16));
        mx = fmaxf(mx, __shfl_xor(mx, 32));
        // defer-max: keep old m while tile max hasn't grown by >8 (exp2 domain -> P <= 256)
        if (!__all(mx <= m_s + 8.f)) {
            float mnew = fmaxf(m_s, mx);
            float alpha = fast_exp2(m_s - mnew);
            l_s *= alpha;
            #pragma unroll
            for (int i = 0; i < 4; i++)
                #pragma unroll
                for (int r = 0; r < 4; r++) accO[i][r] *= alpha;
            m_s = mnew;
        }
        float psum = 0.f;
        bf16x4 ph[4];
        #pragma unroll
        for (int kb = 0; kb < 4; kb++)
            #pragma unroll
            for (int r = 0; r < 4; r++) {
                float pv = fast_exp2(st[kb][r] - m_s);
                psum += pv;
                ph[kb][r] = (bf16)pv;
            }
        psum += __shfl_xor(psum, 16);
        psum += __shfl_xor(psum, 32);
        l_s += psum;
        // O^T += Vt @ P^T : K=16 MFMA, B-fragment (k=l4*4+r, n=l16) == st register layout -> direct feed
        __builtin_amdgcn_s_setprio(1);
        #pragma unroll
        for (int kb = 0; kb < 4; kb++) {
            #pragma unroll
            for (int i = 0; i < 4; i++) {
                bf16x4 avh = v_frag(VhT, i * 16 + l16, kb * 4 + l4);
                accO[i] = mfma16(avh, ph[kb], accO[i]);
            }
        }
        __builtin_amdgcn_s_setprio(0);
    };

    const int NT = SEQ / 64;   // 32, even
    stage(0, 0);
    #pragma unroll 1
    for (int t = 0; t < NT; t += 2) {
        stage((t + 1) * 64, 1);
        asm volatile("s_waitcnt vmcnt(2)" ::: "memory");
        __builtin_amdgcn_sched_barrier(0);
        __builtin_amdgcn_s_barrier();
        compute(KhS[0], VhS[0]);
        asm volatile("" ::: "memory");
        __builtin_amdgcn_s_barrier();
        if (t + 2 < NT) {
            stage((t + 2) * 64, 0);
            asm volatile("s_waitcnt vmcnt(2)" ::: "memory");
        } else {
            asm volatile("s_waitcnt vmcnt(0)" ::: "memory");
        }
        __builtin_amdgcn_sched_barrier(0);
        __builtin_amdgcn_s_barrier();
        compute(KhS[1], VhS[1]);
        asm volatile("" ::: "memory");
        __builtin_amdgcn_s_barrier();
    }

    // epilogue: lane owns q = q0 + wave*16 + l16; d = i*16 + l4*4 + r -> b64 packed
    float inv = 1.f / l_s;
    int q = q0 + wave * 16 + l16;
    #pragma unroll
    for (int i = 0; i < 4; i++) {
        bf16x4 oh4, ol4;
        #pragma unroll
        for (int r = 0; r < 4; r++) { HL sp = split2(accO[i][r] * inv); oh4[r] = sp.h; ol4[r] = sp.l; }
        long o = ((long)(b * SEQ + q)) * DIM + h * 64 + i * 16 + l4 * 4;
        *(bf16x4*)&aoh[o] = oh4;
        *(bf16x4*)&aol[o] = ol4;
    }
}

// ---------------- proj split GEMM (glds, T2-swizzled): C = A@Bt^T + bias + residual -> fp32 ----------------
__global__ __launch_bounds__(256)
void gemm_proj(const bf16* __restrict__ Ah_g, const bf16* __restrict__ Al_g,
               const bf16* __restrict__ Bh_g, const bf16* __restrict__ Bl_g,
               const float* __restrict__ bias, const float* __restrict__ res,
               float* __restrict__ C, int N, int K) {
    __shared__ alignas(16) bf16 Ah[8192], Al[8192], Bh[8192], Bl[8192];
    int tid = threadIdx.x;
    int wave = tid >> 6, lane = tid & 63;
    int l16 = lane & 15, l4 = lane >> 4;
    int wr = (wave >> 1) * 64, wc = (wave & 1) * 64;
    int row0 = blockIdx.y * 128, col0 = blockIdx.x * 128;
    int r8s = lane >> 3;
    int colb = ((lane & 7) ^ r8s) * 8;        // pre-swizzled global 16B chunk
    f32x4 acc[4][4] = {};
    for (int k0 = 0; k0 < K; k0 += 64) {
        #pragma unroll
        for (int p = 0; p < 4; p++) {
            int rl = p * 32 + wave * 8 + r8s;
            int lb = p * 2048 + wave * 512;
            gload16(&Ah_g[(long)(row0 + rl) * K + k0 + colb], &Ah[lb]);
            gload16(&Al_g[(long)(row0 + rl) * K + k0 + colb], &Al[lb]);
            gload16(&Bh_g[(long)(col0 + rl) * K + k0 + colb], &Bh[lb]);
            gload16(&Bl_g[(long)(col0 + rl) * K + k0 + colb], &Bl[lb]);
        }
        __syncthreads();
        #pragma unroll
        for (int ks = 0; ks < 2; ks++) {
            bf16x8 ah[4], al[4], bh[4], bl[4];
            #pragma unroll
            for (int i = 0; i < 4; i++) {
                ah[i] = sw_frag(Ah, wr + i*16 + l16, ks*4 + l4);
                al[i] = sw_frag(Al, wr + i*16 + l16, ks*4 + l4);
            }
            #pragma unroll
            for (int j = 0; j < 4; j++) {
                bh[j] = sw_frag(Bh, wc + j*16 + l16, ks*4 + l4);
                bl[j] = sw_frag(Bl, wc + j*16 + l16, ks*4 + l4);
            }
            #pragma unroll
            for (int i = 0; i < 4; i++)
                #pragma unroll
                for (int j = 0; j < 4; j++) {
                    acc[i][j] = __builtin_amdgcn_mfma_f32_16x16x32_bf16(ah[i], bh[j], acc[i][j], 0, 0, 0);
                    acc[i][j] = __builtin_amdgcn_mfma_f32_16x16x32_bf16(ah[i], bl[j], acc[i][j], 0, 0, 0);
                    acc[i][j] = __builtin_amdgcn_mfma_f32_16x16x32_bf16(al[i], bh[j], acc[i][j], 0, 0, 0);
                }
        }
        __syncthreads();
    }
    #pragma unroll
    for (int i = 0; i < 4; i++)
        #pragma unroll
        for (int r = 0; r < 4; r++) {
            int grow = row0 + wr + i * 16 + l4 * 4 + r;
            #pragma unroll
            for (int j = 0; j < 4; j++) {
                int gcol = col0 + wc + j * 16 + l16;
                long o = (long)grow * N + gcol;
                C[o] = acc[i][j][r] + bias[gcol] + res[o];
            }
        }
}

// ---------------- plain bf16 GEMM (glds staging, T2-swizzled, T1-remapped), tile-templated ----------------
// OUT_MODE 0: bf16 store; 2: fp32 += v; 3: atomicAdd(Cf[rowmap[row]*N+col], roww[row]*v)
// BM/BN: tile shape (default 128x128). Smaller tiles multiply the grid for occupancy on
// small-output GEMMs (mlp2: 256 blocks @128^2 = 1 block/CU -> 64^2 gives 1024 = 4/CU).
template<bool BIAS, bool GELU, bool GATHER, int OUT_MODE, int BM = 128, int BN = 128>
__global__ __launch_bounds__(256)
void gemm_bt(const bf16* __restrict__ A, const bf16* __restrict__ Bt,
             const float* __restrict__ bias,
             bf16* __restrict__ Cbf, float* __restrict__ Cf,
             const int* __restrict__ rowmap, const float* __restrict__ roww,
             int M, int N, int K,
             long eA, long eB, long ebias, long eMap, long eC) {
    int ez = blockIdx.z;
    A += (long)ez * eA; Bt += (long)ez * eB;
    if (BIAS) bias += (long)ez * ebias;
    if (GATHER || OUT_MODE == 3) rowmap += (long)ez * eMap;
    if (OUT_MODE == 3) roww += (long)ez * eMap;
    if (OUT_MODE == 0) Cbf += (long)ez * eC;

    constexpr int MI = BM / 32, NJ = BN / 32;   // per-wave fragment counts == staging phases
    __shared__ alignas(16) bf16 As[BM * 64];
    __shared__ alignas(16) bf16 Bs[BN * 64];
    int tid = threadIdx.x;
    int wave = tid >> 6, lane = tid & 63;
    int l16 = lane & 15, l4 = lane >> 4;
    int wr = (wave >> 1) * (BM / 2), wc = (wave & 1) * (BN / 2);
    int bx, by; xcd_tile(bx, by);
    int row0 = by * BM, col0 = bx * BN;
    int r8s = lane >> 3;
    int colb = ((lane & 7) ^ r8s) * 8;        // pre-swizzled global 16B chunk

    long arow[MI];
    #pragma unroll
    for (int p = 0; p < MI; p++) {
        long gr = row0 + p * 32 + wave * 8 + r8s;
        if (GATHER) gr = rowmap[gr];
        arow[p] = gr;
    }
    f32x4 acc[MI][NJ] = {};
    for (int k0 = 0; k0 < K; k0 += 64) {
        #pragma unroll
        for (int p = 0; p < MI; p++)
            gload16(&A[arow[p] * K + k0 + colb], &As[p * 2048 + wave * 512]);
        #pragma unroll
        for (int p = 0; p < NJ; p++) {
            int rl = p * 32 + wave * 8 + r8s;
            gload16(&Bt[(long)(col0 + rl) * K + k0 + colb], &Bs[p * 2048 + wave * 512]);
        }
        __syncthreads();
        #pragma unroll
        for (int ks = 0; ks < 2; ks++) {
            bf16x8 af[MI], bfr[NJ];
            #pragma unroll
            for (int i = 0; i < MI; i++) af[i]  = sw_frag(As, wr + i*16 + l16, ks*4 + l4);
            #pragma unroll
            for (int j = 0; j < NJ; j++) bfr[j] = sw_frag(Bs, wc + j*16 + l16, ks*4 + l4);
            #pragma unroll
            for (int i = 0; i < MI; i++)
                #pragma unroll
                for (int j = 0; j < NJ; j++)
                    acc[i][j] = __builtin_amdgcn_mfma_f32_16x16x32_bf16(af[i], bfr[j], acc[i][j], 0, 0, 0);
        }
        __syncthreads();
    }
    #pragma unroll
    for (int i = 0; i < MI; i++)
        #pragma unroll
        for (int r = 0; r < 4; r++) {
            int grow = row0 + wr + i * 16 + l4 * 4 + r;
            int st = 0; float sw = 0.f;
            if (OUT_MODE == 3) { st = rowmap[grow]; sw = roww[grow]; }
            #pragma unroll
            for (int j = 0; j < NJ; j++) {
                int gcol = col0 + wc + j * 16 + l16;
                float v = acc[i][j][r];
                if (BIAS) v += bias[gcol];
                if (GELU) v = gelu_exact(v);
                if (OUT_MODE == 0) {
                    Cbf[(long)grow * N + gcol] = (bf16)v;
                } else if (OUT_MODE == 2) {
                    long o = (long)grow * N + gcol;
                    Cf[o] += v;
                } else {
                    atomicAdd(&Cf[(long)st * N + gcol], sw * v);
                }
            }
        }
}

// ---------------- routing (pure fp32, LN inline) + fused x2b store: one wave per token ----------------
__global__ __launch_bounds__(256)
void routing_kernel(const float* __restrict__ xres, const float* __restrict__ g,
                    const float* __restrict__ b, const float* __restrict__ w_route,
                    const float* __restrict__ b_route, const float* __restrict__ w_noise,
                    const float* __restrict__ b_noise, const float* __restrict__ noise,
                    int* __restrict__ topi, float* __restrict__ topp,
                    bf16* __restrict__ x2b) {
    int wave = threadIdx.x >> 6, lane = threadIdx.x & 63;
    long t = (long)blockIdx.x * 4 + wave;
    const float* xr = xres + t * DIM;
    float v[16];
    #pragma unroll
    for (int i = 0; i < 16; i++) v[i] = xr[i * 64 + lane];
    float s = 0.f, s2 = 0.f;
    #pragma unroll
    for (int i = 0; i < 16; i++) { s += v[i]; s2 += v[i] * v[i]; }
    #pragma unroll
    for (int m = 1; m < 64; m <<= 1) { s += __shfl_xor(s, m); s2 += __shfl_xor(s2, m); }
    float mu  = s * (1.f / DIM);
    float var = s2 * (1.f / DIM) - mu * mu;
    float rs  = 1.f / sqrtf(var + 1e-5f);
    float accr[4] = {0.f,0.f,0.f,0.f}, accn[4] = {0.f,0.f,0.f,0.f};
    #pragma unroll
    for (int i = 0; i < 16; i++) {
        int d = i * 64 + lane;
        float n = (v[i] - mu) * rs * g[d] + b[d];
        x2b[t * DIM + d] = (bf16)n;               // fused LN2 output
        #pragma unroll
        for (int e = 0; e < 4; e++) {
            accr[e] += n * w_route[d * 4 + e];
            accn[e] += n * w_noise[d * 4 + e];
        }
    }
    #pragma unroll
    for (int e = 0; e < 4; e++)
        #pragma unroll
        for (int m = 1; m < 64; m <<= 1) {
            accr[e] += __shfl_xor(accr[e], m);
            accn[e] += __shfl_xor(accn[e], m);
        }
    if (lane == 0) {
        float nz[4];
        #pragma unroll
        for (int e = 0; e < 4; e++) {
            float logit = accr[e] + b_route[e];
            float si = accn[e] + b_noise[e];
            float sp = si > 0.f ? si + log1pf(expf(-si)) : log1pf(expf(si));
            nz[e] = logit + noise[t * 4 + e] * sp;
        }
        int i1 = 0;
        #pragma unroll
        for (int e = 1; e < 4; e++) if (nz[e] > nz[i1]) i1 = e;
        int i2 = -1; float v2 = -1e30f;
        #pragma unroll
        for (int e = 0; e < 4; e++) if (e != i1 && nz[e] > v2) { v2 = nz[e]; i2 = e; }
        float ex = expf(v2 - nz[i1]);
        topi[t * 2]     = i1; topi[t * 2 + 1] = i2;
        topp[t * 2]     = 1.f / (1.f + ex);
        topp[t * 2 + 1] = ex / (1.f + ex);
    }
}

// ---------------- dispatch: per-expert ordered token lists (wave e = expert e) ----------------
__global__ __launch_bounds__(256)
void dispatch_kernel(const int* __restrict__ topi, const float* __restrict__ topp,
                     int* __restrict__ sel, float* __restrict__ wgt) {
    int e = threadIdx.x >> 6, lane = threadIdx.x & 63;
    int cnt = 0;
    for (int c = 0; c < T_TOK; c += 64) {
        int t = c + lane;
        int i0 = topi[t * 2], i1 = topi[t * 2 + 1];
        bool m = (i0 == e) || (i1 == e);
        unsigned long long bal = __ballot(m);
        int pos = cnt + __popcll(bal & ((1ull << lane) - 1ull));
        if (m && pos < CAP) {
            sel[e * CAP + pos] = t;
            wgt[e * CAP + pos] = (i0 == e) ? topp[t * 2] : topp[t * 2 + 1];
        }
        cnt += (int)__popcll(bal);
    }
    if (cnt > CAP) cnt = CAP;
    for (int pos = cnt + lane; pos < CAP; pos += 64) {
        sel[e * CAP + pos] = 0;
        wgt[e * CAP + pos] = 0.f;
    }
}

extern "C" void kernel_launch(void* const* d_in, const int* in_sizes, int n_in,
                              void* d_out, int out_size, void* d_ws, size_t ws_size,
                              hipStream_t stream) {
    (void)in_sizes; (void)n_in; (void)out_size; (void)ws_size;
    const float* x       = (const float*)d_in[0];
    const float* noise   = (const float*)d_in[1];
    const float* ln1_g   = (const float*)d_in[2];
    const float* ln1_b   = (const float*)d_in[3];
    const float* ln2_g   = (const float*)d_in[4];
    const float* ln2_b   = (const float*)d_in[5];
    const float* w_qkv   = (const float*)d_in[6];
    const float* w_proj  = (const float*)d_in[7];
    const float* b_proj  = (const float*)d_in[8];
    const float* w_route = (const float*)d_in[9];
    const float* b_route = (const float*)d_in[10];
    const float* w_noise = (const float*)d_in[11];
    const float* b_noise = (const float*)d_in[12];
    const float* we1     = (const float*)d_in[13];
    const float* be1     = (const float*)d_in[14];
    const float* we2     = (const float*)d_in[15];
    const float* be2     = (const float*)d_in[16];
    const float* w_mlp1  = (const float*)d_in[17];
    const float* b_mlp1  = (const float*)d_in[18];
    const float* w_mlp2  = (const float*)d_in[19];
    const float* b_mlp2  = (const float*)d_in[20];
    float* d_outf = (float*)d_out;

    // ---- workspace (80 MB peak) ----
    const size_t MB = 1024 * 1024;
    char* ws = (char*)d_ws;
    // region A (0..16M): x1h/x1l -> aoh/aol -> w_mlp1T/w_mlp2T
    bf16* x1h = (bf16*)(ws);
    bf16* x1l = (bf16*)(ws + 8 * MB);
    bf16* aoh = (bf16*)(ws);
    bf16* aol = (bf16*)(ws + 8 * MB);
    bf16* w_mlp1T = (bf16*)(ws);
    bf16* w_mlp2T = (bf16*)(ws + 8 * MB);
    // region B (16..28M): wqkvh/wqkvl -> we1T/we2T/h_e
    bf16* wqkvh = (bf16*)(ws + 16 * MB);
    bf16* wqkvl = (bf16*)(ws + 22 * MB);
    bf16* we1T  = (bf16*)(ws + 16 * MB);
    bf16* we2T  = (bf16*)(ws + 18 * MB);
    bf16* h_e   = (bf16*)(ws + 20 * MB);
    // region C (28..32M): wprojh/wprojl
    bf16* wprojh = (bf16*)(ws + 28 * MB);
    bf16* wprojl = (bf16*)(ws + 30 * MB);
    // region D (32..56M): Qh/Kh -> h_mlp (32M overlay after flash)
    bf16* Qh = (bf16*)(ws + 32 * MB);
    bf16* Kh = (bf16*)(ws + 40 * MB);
    bf16* h_mlp = (bf16*)(ws + 32 * MB);
    // region E (64..80M): VtH (8M, dead after flash) -> x2b + routing buffers
    bf16*  VtH  = (bf16*)(ws + 64 * MB);
    bf16*  x2b  = (bf16*)(ws + 64 * MB);
    int*   topi = (int*)(ws + 72 * MB);
    float* topp = (float*)(ws + 72 * MB + 32768);
    int*   sel  = (int*)(ws + 72 * MB + 65536);
    float* wgt  = (float*)(ws + 72 * MB + 98304);

    // ---- phase 1: LN1-split, weight splits ----
    ln_split_kernel<<<T_TOK/4, 256, 0, stream>>>(x, ln1_g, ln1_b, x1h, x1l);
    split_pair_kernel<<<(3*DIM*DIM)/1024, 256, 0, stream>>>(w_qkv, wqkvh, wqkvl);
    split_pair_kernel<<<(DIM*DIM)/1024,   256, 0, stream>>>(w_proj, wprojh, wprojl);

    // ---- phase 2: qkv GEMM (epilogue: Q(x log2e/8)/K hi planes, V hi-only Vt) ----
    gemm_qkv<<<dim3(3*DIM/128, T_TOK/128), 256, 0, stream>>>(
        x1h, x1l, wqkvh, wqkvl, Qh, Kh, VtH);

    // ---- phase 3: flash attention (8-wave blocks, 128 q-rows; bid&31 = bh -> XCD locality) ----
    flash_attn<<<dim3(32 * (SEQ/128)), 512, 0, stream>>>(Qh, Kh, VtH, aoh, aol);

    // ---- phase 4: proj + bias + residual -> d_out (fp32 stream) ----
    gemm_proj<<<dim3(DIM/128, T_TOK/128), 256, 0, stream>>>(
        aoh, aol, wprojh, wprojl, b_proj, x, d_outf, DIM, DIM);

    // ---- phase 5: routing (fused LN2 -> x2b) + dispatch ----
    routing_kernel<<<T_TOK/4, 256, 0, stream>>>(d_outf, ln2_g, ln2_b, w_route, b_route,
                                                w_noise, b_noise, noise, topi, topp, x2b);
    dispatch_kernel<<<1, 256, 0, stream>>>(topi, topp, sel, wgt);

    // ---- phase 6: weight transposes (aoh/x1 regions dead) ----
    transpose_conv_kernel<<<dim3(MLPH/32, DIM/32, 1),    256, 0, stream>>>(w_mlp1, w_mlp1T, DIM, MLPH);
    transpose_conv_kernel<<<dim3(DIM/32, MLPH/32, 1),    256, 0, stream>>>(w_mlp2, w_mlp2T, MLPH, DIM);
    transpose_conv_kernel<<<dim3(MOEH/32, DIM/32, NEXP), 256, 0, stream>>>(we1, we1T, DIM, MOEH);
    transpose_conv_kernel<<<dim3(DIM/32, MOEH/32, NEXP), 256, 0, stream>>>(we2, we2T, MOEH, DIM);

    // ---- phase 7: dense MLP (mlp1 bf16; mlp2 fp32 += into d_out, 64x64 tiles -> 1024 blocks) ----
    gemm_bt<true,true,false,0><<<dim3(MLPH/128, T_TOK/128), 256, 0, stream>>>(
        x2b, w_mlp1T, b_mlp1, h_mlp, nullptr, nullptr, nullptr, T_TOK, MLPH, DIM,
        0, 0, 0, 0, 0);
    gemm_bt<true,false,false,2,64,64><<<dim3(DIM/64, T_TOK/64), 256, 0, stream>>>(
        h_mlp, w_mlp2T, b_mlp2, nullptr, d_outf, nullptr, nullptr, T_TOK, DIM, MLPH,
        0, 0, 0, 0, 0);

    // ---- phase 8: MoE experts, batched over blockIdx.z ----
    gemm_bt<true,true,true,0><<<dim3(MOEH/128, CAP/128, NEXP), 256, 0, stream>>>(
        x2b, we1T, be1, h_e, nullptr, sel, nullptr, CAP, MOEH, DIM,
        0, (long)MOEH*DIM, MOEH, CAP, (long)CAP*MOEH);
    gemm_bt<true,false,false,3><<<dim3(DIM/128, CAP/128, NEXP), 256, 0, stream>>>(
        h_e, we2T, be2, nullptr, d_outf, sel, wgt, CAP, DIM, MOEH,
        (long)CAP*MOEH, (long)DIM*MOEH, DIM, CAP, 0);
}

// Round 15
// 581.641 us; speedup vs baseline: 1.0845x; 1.0845x over previous
//
#include <hip/hip_runtime.h>
#include <hip/hip_bf16.h>
#include <math.h>

typedef __bf16 bf16;
typedef __bf16 bf16x4 __attribute__((ext_vector_type(4)));
typedef __bf16 bf16x8 __attribute__((ext_vector_type(8)));
typedef float  f32x4  __attribute__((ext_vector_type(4)));
typedef short  s16x4  __attribute__((ext_vector_type(4)));

#define T_TOK 4096
#define DIM   1024
#define NHEAD 16
#define SEQ   2048
#define NEXP  4
#define CAP   2048
#define MLPH  4096
#define MOEH  256

__device__ __forceinline__ float gelu_exact(float v) {
    return 0.5f * v * (1.f + erff(v * 0.70710678118654752f));
}

struct HL { bf16 h, l; };
__device__ __forceinline__ HL split2(float v) {
    HL r; r.h = (bf16)v; r.l = (bf16)(v - (float)r.h); return r;
}

__device__ __forceinline__ float fast_exp2(float x) {
#if __has_builtin(__builtin_amdgcn_exp2f)
    return __builtin_amdgcn_exp2f(x);
#else
    return exp2f(x);
#endif
}

// K=16 bf16 MFMA: B-fragment layout (k = l4*4+r, n = l16) matches the QK^T C-layout -> direct P feed
__device__ __forceinline__ f32x4 mfma16(bf16x4 a, bf16x4 b, f32x4 c) {
    return __builtin_amdgcn_mfma_f32_16x16x16bf16_1k(
        __builtin_bit_cast(s16x4, a), __builtin_bit_cast(s16x4, b), c, 0, 0, 0);
}

// async global->LDS, 16B per lane; LDS dest = wave-uniform base + lane*16
__device__ __forceinline__ void gload16(const bf16* gptr, bf16* lptr) {
    __builtin_amdgcn_global_load_lds(
        (const __attribute__((address_space(1))) unsigned int*)gptr,
        (__attribute__((address_space(3))) unsigned int*)lptr,
        16, 0, 0);
}

// swizzled fragment read: logical (row, 16B-chunk cc) stored at chunk cc^(row&7)
// (staging pre-swizzles the GLOBAL source chunk by r8, LDS dest stays linear -> both-sides swizzle)
__device__ __forceinline__ bf16x8 sw_frag(const bf16* arr, int row, int cc) {
    return *(const bf16x8*)&arr[row * 64 + ((cc ^ (row & 7)) * 8)];
}
// V fragment read (b64): quad q (4 keys) of row d stored at 8B slot q^(d&15)
// -> per 16-lane quarter the 16 slots are a bijection onto all 16 bank-pairs: conflict-free
__device__ __forceinline__ bf16x4 v_frag(const bf16* arr, int d, int q) {
    return *(const bf16x4*)&arr[d * 64 + ((q ^ (d & 15)) * 4)];
}

// T1: bijective XCD-aware tile remap — applied ONLY to gemm_bt (within-run counter proof:
// mlp2 FETCH 143->49 MB). qkv/proj measured FETCH +35% with it -> plain mapping there.
__device__ __forceinline__ void xcd_tile(int& bx, int& by) {
    int gx = gridDim.x;
    int nwg = gx * gridDim.y;
    int flat = blockIdx.y * gx + blockIdx.x;
    int q = nwg >> 3, r = nwg & 7;
    int xcd = flat & 7, loc = flat >> 3;
    int swz = (xcd < r ? xcd * (q + 1) : r * (q + 1) + (xcd - r) * q) + loc;
    bx = swz % gx; by = swz / gx;
}

// ---------------- LN1 -> hi/lo bf16 planes: one wave per token ----------------
__global__ __launch_bounds__(256)
void ln_split_kernel(const float* __restrict__ x, const float* __restrict__ g,
                     const float* __restrict__ b, bf16* __restrict__ oh, bf16* __restrict__ ol) {
    int wave = threadIdx.x >> 6, lane = threadIdx.x & 63;
    long t = (long)blockIdx.x * 4 + wave;
    const float* xr = x + t * DIM;
    float v[16];
    #pragma unroll
    for (int i = 0; i < 16; i++) v[i] = xr[i * 64 + lane];
    float s = 0.f, s2 = 0.f;
    #pragma unroll
    for (int i = 0; i < 16; i++) { s += v[i]; s2 += v[i] * v[i]; }
    #pragma unroll
    for (int m = 1; m < 64; m <<= 1) { s += __shfl_xor(s, m); s2 += __shfl_xor(s2, m); }
    float mu  = s * (1.f / DIM);
    float var = s2 * (1.f / DIM) - mu * mu;
    float rs  = 1.f / sqrtf(var + 1e-5f);
    #pragma unroll
    for (int i = 0; i < 16; i++) {
        int d = i * 64 + lane;
        HL sp = split2((v[i] - mu) * rs * g[d] + b[d]);
        oh[t * DIM + d] = sp.h; ol[t * DIM + d] = sp.l;
    }
}

// ---------------- elementwise fp32 -> hi/lo planes ----------------
__global__ __launch_bounds__(256)
void split_pair_kernel(const float* __restrict__ in, bf16* __restrict__ h, bf16* __restrict__ l) {
    long i0 = ((long)blockIdx.x * 256 + threadIdx.x) * 4;
    f32x4 v = *(const f32x4*)&in[i0];
    bf16x4 vh, vl;
    #pragma unroll
    for (int j = 0; j < 4; j++) { HL sp = split2(v[j]); vh[j] = sp.h; vl[j] = sp.l; }
    *(bf16x4*)&h[i0] = vh; *(bf16x4*)&l[i0] = vl;
}

// ---------------- transpose fp32 -> bf16 (32x32 tiles, batched in z) ----------------
__global__ __launch_bounds__(256)
void transpose_conv_kernel(const float* __restrict__ in, bf16* __restrict__ out, int R, int C) {
    __shared__ bf16 tile[32][33];
    long bo = (long)blockIdx.z * R * C;
    in += bo; out += bo;
    int c0 = blockIdx.x * 32, r0 = blockIdx.y * 32;
    int tx = threadIdx.x & 31, ty = threadIdx.x >> 5;
    #pragma unroll
    for (int i = 0; i < 32; i += 8)
        tile[ty + i][tx] = (bf16)in[(long)(r0 + ty + i) * C + c0 + tx];
    __syncthreads();
    #pragma unroll
    for (int i = 0; i < 32; i += 8)
        out[(long)(c0 + ty + i) * R + r0 + tx] = tile[tx][ty + i];
}

// ---------------- qkv split GEMM: glds staging (T2-swizzled); epilogue -> Q/K hi planes + hi-only Vt ----------------
// Q pre-scale folds log2(e): softmax downstream runs in exp2 domain.
// Attention path runs bf16-hi only (Q_lo/K_lo/V_lo dropped; each adds ~2^-9 rel err, >=10x under
// the 0.03125 absmax which is MLP-dominated).
// V stored transposed VtH[bh][d][s] with odd-d quad swap (s^4) so flash's conflict-free
// v_frag layout (quad q of row d at slot q^(d&15)) stages with linear global_load_lds.
__global__ __launch_bounds__(256)
void gemm_qkv(const bf16* __restrict__ Ah_g, const bf16* __restrict__ Al_g,
              const bf16* __restrict__ Bh_g, const bf16* __restrict__ Bl_g,
              bf16* __restrict__ Qh_g, bf16* __restrict__ Kh_g,
              bf16* __restrict__ VtH) {
    const int K = DIM;
    __shared__ alignas(16) bf16 Ah[8192], Al[8192], Bh[8192], Bl[8192];
    int tid = threadIdx.x;
    int wave = tid >> 6, lane = tid & 63;
    int l16 = lane & 15, l4 = lane >> 4;
    int wr = (wave >> 1) * 64, wc = (wave & 1) * 64;
    int row0 = blockIdx.y * 128, col0 = blockIdx.x * 128;
    int r8s = lane >> 3;                      // row within 8-row staging group (== row&7)
    int colb = ((lane & 7) ^ r8s) * 8;        // pre-swizzled global 16B chunk
    f32x4 acc[4][4] = {};
    for (int k0 = 0; k0 < K; k0 += 64) {
        #pragma unroll
        for (int p = 0; p < 4; p++) {
            int rl = p * 32 + wave * 8 + r8s;
            int lb = p * 2048 + wave * 512;
            gload16(&Ah_g[(long)(row0 + rl) * K + k0 + colb], &Ah[lb]);
            gload16(&Al_g[(long)(row0 + rl) * K + k0 + colb], &Al[lb]);
            gload16(&Bh_g[(long)(col0 + rl) * K + k0 + colb], &Bh[lb]);
            gload16(&Bl_g[(long)(col0 + rl) * K + k0 + colb], &Bl[lb]);
        }
        __syncthreads();
        #pragma unroll
        for (int ks = 0; ks < 2; ks++) {
            bf16x8 ah[4], al[4], bh[4], bl[4];
            #pragma unroll
            for (int i = 0; i < 4; i++) {
                ah[i] = sw_frag(Ah, wr + i*16 + l16, ks*4 + l4);
                al[i] = sw_frag(Al, wr + i*16 + l16, ks*4 + l4);
            }
            #pragma unroll
            for (int j = 0; j < 4; j++) {
                bh[j] = sw_frag(Bh, wc + j*16 + l16, ks*4 + l4);
                bl[j] = sw_frag(Bl, wc + j*16 + l16, ks*4 + l4);
            }
            #pragma unroll
            for (int i = 0; i < 4; i++)
                #pragma unroll
                for (int j = 0; j < 4; j++) {
                    acc[i][j] = __builtin_amdgcn_mfma_f32_16x16x32_bf16(ah[i], bh[j], acc[i][j], 0, 0, 0);
                    acc[i][j] = __builtin_amdgcn_mfma_f32_16x16x32_bf16(ah[i], bl[j], acc[i][j], 0, 0, 0);
                    acc[i][j] = __builtin_amdgcn_mfma_f32_16x16x32_bf16(al[i], bh[j], acc[i][j], 0, 0, 0);
                }
        }
        __syncthreads();
    }
    if (col0 < 2048) {   // Q/K columns -> hi planes [bh][s][64]; Q pre-scaled by log2(e)/8 (exp2-domain)
        bool isQ = (col0 < 1024);
        bf16* oh = isQ ? Qh_g : Kh_g;
        float qscale = isQ ? 0.18033688011112043f : 1.0f;
        #pragma unroll
        for (int i = 0; i < 4; i++)
            #pragma unroll
            for (int r = 0; r < 4; r++) {
                int t = row0 + wr + i * 16 + l4 * 4 + r;
                int bq = t >> 11, s = t & 2047;
                #pragma unroll
                for (int j = 0; j < 4; j++) {
                    int col = (col0 + wc + j * 16 + l16) & 1023;
                    int hh = col >> 6, dl = col & 63;
                    long o = ((long)(bq * NHEAD + hh) * SEQ + s) * 64 + dl;
                    oh[o] = (bf16)(acc[i][j][r] * qscale);
                }
            }
    } else {             // V columns -> hi-only transposed VtH[bh][d][s], r-packed b64 stores; odd-d quad swap
        #pragma unroll
        for (int i = 0; i < 4; i++) {
            int s0 = row0 + wr + i * 16 + l4 * 4;
            int b = s0 >> 11, sl = s0 & 2047;
            #pragma unroll
            for (int j = 0; j < 4; j++) {
                int d = col0 - 2048 + wc + j * 16 + l16;
                int h = d >> 6, dl = d & 63;
                long base = ((long)(b * NHEAD + h) * 64 + dl) * SEQ + (sl ^ ((dl & 1) << 2));
                bf16x4 vh;
                #pragma unroll
                for (int r = 0; r < 4; r++) vh[r] = (bf16)acc[i][j][r];
                *(bf16x4*)&VtH[base] = vh;
            }
        }
    }
}

// ---------------- flash attention: 8-wave blocks (128 q-rows), double-buffered K/V, counted vmcnt ----------------
// bf16-hi attention: S = K_hi x Q_hi (8 MFMAs/tile); PV = V_hi x P via K=16 MFMA with P fed
// straight from the QK accumulator (B-fragment k=l4*4+r == st layout; no shuffle, no LDS).
__global__ __launch_bounds__(512, 4)
void flash_attn(const bf16* __restrict__ Qh_g,
                const bf16* __restrict__ Kh_g,
                const bf16* __restrict__ VtH_g,
                bf16* __restrict__ aoh, bf16* __restrict__ aol) {
    __shared__ alignas(16) bf16 KhS[2][4096], VhS[2][4096];
    int tid = threadIdx.x;
    int wave = tid >> 6, lane = tid & 63;   // wave in [0,8)
    int l16 = lane & 15, l4 = lane >> 4;
    int bid = blockIdx.x;
    int bh = bid & 31;            // same-bh blocks share XCD (bid%8 == bh%8) -> K/V stay in that L2
    int b = bh >> 4, h = bh & 15;
    int q0 = (bid >> 5) * 128;

    // Q_hi fragments (pre-scaled by log2(e)/8 at producer) straight into registers
    bf16x8 qfh[2];
    {
        const bf16* qh = Qh_g + ((long)bh * SEQ + q0 + wave * 16 + l16) * 64;
        #pragma unroll
        for (int ks = 0; ks < 2; ks++)
            qfh[ks] = *(const bf16x8*)&qh[ks * 32 + l4 * 8];
    }
    int r8 = lane >> 3;
    int c8 = lane & 7;
    const bf16* kh_g = Kh_g + (long)bh * SEQ * 64;
    const bf16* vh_g = VtH_g + (long)bh * 64 * SEQ;

    float m_s = -1e30f, l_s = 0.f;
    f32x4 accO[4] = {};

    // stage one 64-key tile (2 gload16 per wave; wave w owns rows w*8..w*8+7) into buffer bsel
    auto stage = [&](int c0, int bsel) {
        int R0 = wave * 8;
        int row = R0 + r8;
        int ksw = (c8 ^ r8) * 8;                               // K: 16B chunk ^ (row&7)
        int vsw = (c8 ^ ((wave * 4 + (r8 >> 1)) & 7)) * 8;     // V: chunk ^ ((d>>1)&7); bit0 via global quad swap
        gload16(&kh_g[(long)(c0 + row) * 64 + ksw], &KhS[bsel][R0 * 64]);
        gload16(&vh_g[(long)row * SEQ + c0 + vsw], &VhS[bsel][R0 * 64]);
    };

    // one tile's compute on the given buffers
    auto compute = [&](const bf16* KhT, const bf16* VhT) {
        // S^T[key][q] = K_hi Q_hi^T for keys [0,64), q-cols [wave*16, +16)  (exp2 domain)
        f32x4 st[4] = {};
        __builtin_amdgcn_s_setprio(1);
        #pragma unroll
        for (int ks = 0; ks < 2; ks++) {
            #pragma unroll
            for (int i = 0; i < 4; i++) {
                bf16x8 akh = sw_frag(KhT, i * 16 + l16, ks * 4 + l4);
                st[i] = __builtin_amdgcn_mfma_f32_16x16x32_bf16(akh, qfh[ks], st[i], 0, 0, 0);
            }
        }
        __builtin_amdgcn_s_setprio(0);
        // online softmax over this lane's q-column (16 keys in-reg + 2 shuffles over l4)
        float mx = st[0][0];
        #pragma unroll
        for (int i = 0; i < 4; i++)
            #pragma unroll
            for (int r = 0; r < 4; r++) mx = fmaxf(mx, st[i][r]);
        mx = fmaxf(mx, __shfl_xor(mx, 16));
        mx = fmaxf(mx, __shfl_xor(mx, 32));
        // defer-max: keep old m while tile max hasn't grown by >8 (exp2 domain -> P <= 256)
        if (!__all(mx <= m_s + 8.f)) {
            float mnew = fmaxf(m_s, mx);
            float alpha = fast_exp2(m_s - mnew);
            l_s *= alpha;
            #pragma unroll
            for (int i = 0; i < 4; i++)
                #pragma unroll
                for (int r = 0; r < 4; r++) accO[i][r] *= alpha;
            m_s = mnew;
        }
        float psum = 0.f;
        bf16x4 ph[4];
        #pragma unroll
        for (int kb = 0; kb < 4; kb++)
            #pragma unroll
            for (int r = 0; r < 4; r++) {
                float pv = fast_exp2(st[kb][r] - m_s);
                psum += pv;
                ph[kb][r] = (bf16)pv;
            }
        psum += __shfl_xor(psum, 16);
        psum += __shfl_xor(psum, 32);
        l_s += psum;
        // O^T += Vt @ P^T : K=16 MFMA, B-fragment (k=l4*4+r, n=l16) == st register layout -> direct feed
        __builtin_amdgcn_s_setprio(1);
        #pragma unroll
        for (int kb = 0; kb < 4; kb++) {
            #pragma unroll
            for (int i = 0; i < 4; i++) {
                bf16x4 avh = v_frag(VhT, i * 16 + l16, kb * 4 + l4);
                accO[i] = mfma16(avh, ph[kb], accO[i]);
            }
        }
        __builtin_amdgcn_s_setprio(0);
    };

    const int NT = SEQ / 64;   // 32, even
    stage(0, 0);
    #pragma unroll 1
    for (int t = 0; t < NT; t += 2) {
        stage((t + 1) * 64, 1);
        asm volatile("s_waitcnt vmcnt(2)" ::: "memory");
        __builtin_amdgcn_sched_barrier(0);
        __builtin_amdgcn_s_barrier();
        compute(KhS[0], VhS[0]);
        asm volatile("" ::: "memory");
        __builtin_amdgcn_s_barrier();
        if (t + 2 < NT) {
            stage((t + 2) * 64, 0);
            asm volatile("s_waitcnt vmcnt(2)" ::: "memory");
        } else {
            asm volatile("s_waitcnt vmcnt(0)" ::: "memory");
        }
        __builtin_amdgcn_sched_barrier(0);
        __builtin_amdgcn_s_barrier();
        compute(KhS[1], VhS[1]);
        asm volatile("" ::: "memory");
        __builtin_amdgcn_s_barrier();
    }

    // epilogue: lane owns q = q0 + wave*16 + l16; d = i*16 + l4*4 + r -> b64 packed
    float inv = 1.f / l_s;
    int q = q0 + wave * 16 + l16;
    #pragma unroll
    for (int i = 0; i < 4; i++) {
        bf16x4 oh4, ol4;
        #pragma unroll
        for (int r = 0; r < 4; r++) { HL sp = split2(accO[i][r] * inv); oh4[r] = sp.h; ol4[r] = sp.l; }
        long o = ((long)(b * SEQ + q)) * DIM + h * 64 + i * 16 + l4 * 4;
        *(bf16x4*)&aoh[o] = oh4;
        *(bf16x4*)&aol[o] = ol4;
    }
}

// ---------------- proj split GEMM (glds, T2-swizzled): C = A@Bt^T + bias + residual -> fp32 ----------------
__global__ __launch_bounds__(256)
void gemm_proj(const bf16* __restrict__ Ah_g, const bf16* __restrict__ Al_g,
               const bf16* __restrict__ Bh_g, const bf16* __restrict__ Bl_g,
               const float* __restrict__ bias, const float* __restrict__ res,
               float* __restrict__ C, int N, int K) {
    __shared__ alignas(16) bf16 Ah[8192], Al[8192], Bh[8192], Bl[8192];
    int tid = threadIdx.x;
    int wave = tid >> 6, lane = tid & 63;
    int l16 = lane & 15, l4 = lane >> 4;
    int wr = (wave >> 1) * 64, wc = (wave & 1) * 64;
    int row0 = blockIdx.y * 128, col0 = blockIdx.x * 128;
    int r8s = lane >> 3;
    int colb = ((lane & 7) ^ r8s) * 8;        // pre-swizzled global 16B chunk
    f32x4 acc[4][4] = {};
    for (int k0 = 0; k0 < K; k0 += 64) {
        #pragma unroll
        for (int p = 0; p < 4; p++) {
            int rl = p * 32 + wave * 8 + r8s;
            int lb = p * 2048 + wave * 512;
            gload16(&Ah_g[(long)(row0 + rl) * K + k0 + colb], &Ah[lb]);
            gload16(&Al_g[(long)(row0 + rl) * K + k0 + colb], &Al[lb]);
            gload16(&Bh_g[(long)(col0 + rl) * K + k0 + colb], &Bh[lb]);
            gload16(&Bl_g[(long)(col0 + rl) * K + k0 + colb], &Bl[lb]);
        }
        __syncthreads();
        #pragma unroll
        for (int ks = 0; ks < 2; ks++) {
            bf16x8 ah[4], al[4], bh[4], bl[4];
            #pragma unroll
            for (int i = 0; i < 4; i++) {
                ah[i] = sw_frag(Ah, wr + i*16 + l16, ks*4 + l4);
                al[i] = sw_frag(Al, wr + i*16 + l16, ks*4 + l4);
            }
            #pragma unroll
            for (int j = 0; j < 4; j++) {
                bh[j] = sw_frag(Bh, wc + j*16 + l16, ks*4 + l4);
                bl[j] = sw_frag(Bl, wc + j*16 + l16, ks*4 + l4);
            }
            #pragma unroll
            for (int i = 0; i < 4; i++)
                #pragma unroll
                for (int j = 0; j < 4; j++) {
                    acc[i][j] = __builtin_amdgcn_mfma_f32_16x16x32_bf16(ah[i], bh[j], acc[i][j], 0, 0, 0);
                    acc[i][j] = __builtin_amdgcn_mfma_f32_16x16x32_bf16(ah[i], bl[j], acc[i][j], 0, 0, 0);
                    acc[i][j] = __builtin_amdgcn_mfma_f32_16x16x32_bf16(al[i], bh[j], acc[i][j], 0, 0, 0);
                }
        }
        __syncthreads();
    }
    #pragma unroll
    for (int i = 0; i < 4; i++)
        #pragma unroll
        for (int r = 0; r < 4; r++) {
            int grow = row0 + wr + i * 16 + l4 * 4 + r;
            #pragma unroll
            for (int j = 0; j < 4; j++) {
                int gcol = col0 + wc + j * 16 + l16;
                long o = (long)grow * N + gcol;
                C[o] = acc[i][j][r] + bias[gcol] + res[o];
            }
        }
}

// ---------------- plain bf16 GEMM (glds staging, T2-swizzled, T1-remapped), expert-batched via blockIdx.z ----------------
// OUT_MODE 0: bf16 store; 2: fp32 += v; 3: atomicAdd(Cf[rowmap[row]*N+col], roww[row]*v)
template<bool BIAS, bool GELU, bool GATHER, int OUT_MODE>
__global__ __launch_bounds__(256)
void gemm_bt(const bf16* __restrict__ A, const bf16* __restrict__ Bt,
             const float* __restrict__ bias,
             bf16* __restrict__ Cbf, float* __restrict__ Cf,
             const int* __restrict__ rowmap, const float* __restrict__ roww,
             int M, int N, int K,
             long eA, long eB, long ebias, long eMap, long eC) {
    int ez = blockIdx.z;
    A += (long)ez * eA; Bt += (long)ez * eB;
    if (BIAS) bias += (long)ez * ebias;
    if (GATHER || OUT_MODE == 3) rowmap += (long)ez * eMap;
    if (OUT_MODE == 3) roww += (long)ez * eMap;
    if (OUT_MODE == 0) Cbf += (long)ez * eC;

    __shared__ alignas(16) bf16 As[8192];
    __shared__ alignas(16) bf16 Bs[8192];
    int tid = threadIdx.x;
    int wave = tid >> 6, lane = tid & 63;
    int l16 = lane & 15, l4 = lane >> 4;
    int wr = (wave >> 1) * 64, wc = (wave & 1) * 64;
    int bx, by; xcd_tile(bx, by);
    int row0 = by * 128, col0 = bx * 128;
    int r8s = lane >> 3;
    int colb = ((lane & 7) ^ r8s) * 8;        // pre-swizzled global 16B chunk

    long arow[4];
    #pragma unroll
    for (int p = 0; p < 4; p++) {
        long gr = row0 + p * 32 + wave * 8 + r8s;
        if (GATHER) gr = rowmap[gr];
        arow[p] = gr;
    }
    f32x4 acc[4][4] = {};
    for (int k0 = 0; k0 < K; k0 += 64) {
        #pragma unroll
        for (int p = 0; p < 4; p++) {
            int rl = p * 32 + wave * 8 + r8s;
            int lb = p * 2048 + wave * 512;
            gload16(&A[arow[p] * K + k0 + colb], &As[lb]);
            gload16(&Bt[(long)(col0 + rl) * K + k0 + colb], &Bs[lb]);
        }
        __syncthreads();
        #pragma unroll
        for (int ks = 0; ks < 2; ks++) {
            bf16x8 af[4], bfr[4];
            #pragma unroll
            for (int i = 0; i < 4; i++) af[i]  = sw_frag(As, wr + i*16 + l16, ks*4 + l4);
            #pragma unroll
            for (int j = 0; j < 4; j++) bfr[j] = sw_frag(Bs, wc + j*16 + l16, ks*4 + l4);
            #pragma unroll
            for (int i = 0; i < 4; i++)
                #pragma unroll
                for (int j = 0; j < 4; j++)
                    acc[i][j] = __builtin_amdgcn_mfma_f32_16x16x32_bf16(af[i], bfr[j], acc[i][j], 0, 0, 0);
        }
        __syncthreads();
    }
    #pragma unroll
    for (int i = 0; i < 4; i++)
        #pragma unroll
        for (int r = 0; r < 4; r++) {
            int grow = row0 + wr + i * 16 + l4 * 4 + r;
            int st = 0; float sw = 0.f;
            if (OUT_MODE == 3) { st = rowmap[grow]; sw = roww[grow]; }
            #pragma unroll
            for (int j = 0; j < 4; j++) {
                int gcol = col0 + wc + j * 16 + l16;
                float v = acc[i][j][r];
                if (BIAS) v += bias[gcol];
                if (GELU) v = gelu_exact(v);
                if (OUT_MODE == 0) {
                    Cbf[(long)grow * N + gcol] = (bf16)v;
                } else if (OUT_MODE == 2) {
                    long o = (long)grow * N + gcol;
                    Cf[o] += v;
                } else {
                    atomicAdd(&Cf[(long)st * N + gcol], sw * v);
                }
            }
        }
}

// ---------------- routing (pure fp32, LN inline) + fused x2b store: one wave per token ----------------
__global__ __launch_bounds__(256)
void routing_kernel(const float* __restrict__ xres, const float* __restrict__ g,
                    const float* __restrict__ b, const float* __restrict__ w_route,
                    const float* __restrict__ b_route, const float* __restrict__ w_noise,
                    const float* __restrict__ b_noise, const float* __restrict__ noise,
                    int* __restrict__ topi, float* __restrict__ topp,
                    bf16* __restrict__ x2b) {
    int wave = threadIdx.x >> 6, lane = threadIdx.x & 63;
    long t = (long)blockIdx.x * 4 + wave;
    const float* xr = xres + t * DIM;
    float v[16];
    #pragma unroll
    for (int i = 0; i < 16; i++) v[i] = xr[i * 64 + lane];
    float s = 0.f, s2 = 0.f;
    #pragma unroll
    for (int i = 0; i < 16; i++) { s += v[i]; s2 += v[i] * v[i]; }
    #pragma unroll
    for (int m = 1; m < 64; m <<= 1) { s += __shfl_xor(s, m); s2 += __shfl_xor(s2, m); }
    float mu  = s * (1.f / DIM);
    float var = s2 * (1.f / DIM) - mu * mu;
    float rs  = 1.f / sqrtf(var + 1e-5f);
    float accr[4] = {0.f,0.f,0.f,0.f}, accn[4] = {0.f,0.f,0.f,0.f};
    #pragma unroll
    for (int i = 0; i < 16; i++) {
        int d = i * 64 + lane;
        float n = (v[i] - mu) * rs * g[d] + b[d];
        x2b[t * DIM + d] = (bf16)n;               // fused LN2 output
        #pragma unroll
        for (int e = 0; e < 4; e++) {
            accr[e] += n * w_route[d * 4 + e];
            accn[e] += n * w_noise[d * 4 + e];
        }
    }
    #pragma unroll
    for (int e = 0; e < 4; e++)
        #pragma unroll
        for (int m = 1; m < 64; m <<= 1) {
            accr[e] += __shfl_xor(accr[e], m);
            accn[e] += __shfl_xor(accn[e], m);
        }
    if (lane == 0) {
        float nz[4];
        #pragma unroll
        for (int e = 0; e < 4; e++) {
            float logit = accr[e] + b_route[e];
            float si = accn[e] + b_noise[e];
            float sp = si > 0.f ? si + log1pf(expf(-si)) : log1pf(expf(si));
            nz[e] = logit + noise[t * 4 + e] * sp;
        }
        int i1 = 0;
        #pragma unroll
        for (int e = 1; e < 4; e++) if (nz[e] > nz[i1]) i1 = e;
        int i2 = -1; float v2 = -1e30f;
        #pragma unroll
        for (int e = 0; e < 4; e++) if (e != i1 && nz[e] > v2) { v2 = nz[e]; i2 = e; }
        float ex = expf(v2 - nz[i1]);
        topi[t * 2]     = i1; topi[t * 2 + 1] = i2;
        topp[t * 2]     = 1.f / (1.f + ex);
        topp[t * 2 + 1] = ex / (1.f + ex);
    }
}

// ---------------- dispatch: per-expert ordered token lists (wave e = expert e) ----------------
__global__ __launch_bounds__(256)
void dispatch_kernel(const int* __restrict__ topi, const float* __restrict__ topp,
                     int* __restrict__ sel, float* __restrict__ wgt) {
    int e = threadIdx.x >> 6, lane = threadIdx.x & 63;
    int cnt = 0;
    for (int c = 0; c < T_TOK; c += 64) {
        int t = c + lane;
        int i0 = topi[t * 2], i1 = topi[t * 2 + 1];
        bool m = (i0 == e) || (i1 == e);
        unsigned long long bal = __ballot(m);
        int pos = cnt + __popcll(bal & ((1ull << lane) - 1ull));
        if (m && pos < CAP) {
            sel[e * CAP + pos] = t;
            wgt[e * CAP + pos] = (i0 == e) ? topp[t * 2] : topp[t * 2 + 1];
        }
        cnt += (int)__popcll(bal);
    }
    if (cnt > CAP) cnt = CAP;
    for (int pos = cnt + lane; pos < CAP; pos += 64) {
        sel[e * CAP + pos] = 0;
        wgt[e * CAP + pos] = 0.f;
    }
}

extern "C" void kernel_launch(void* const* d_in, const int* in_sizes, int n_in,
                              void* d_out, int out_size, void* d_ws, size_t ws_size,
                              hipStream_t stream) {
    (void)in_sizes; (void)n_in; (void)out_size; (void)ws_size;
    const float* x       = (const float*)d_in[0];
    const float* noise   = (const float*)d_in[1];
    const float* ln1_g   = (const float*)d_in[2];
    const float* ln1_b   = (const float*)d_in[3];
    const float* ln2_g   = (const float*)d_in[4];
    const float* ln2_b   = (const float*)d_in[5];
    const float* w_qkv   = (const float*)d_in[6];
    const float* w_proj  = (const float*)d_in[7];
    const float* b_proj  = (const float*)d_in[8];
    const float* w_route = (const float*)d_in[9];
    const float* b_route = (const float*)d_in[10];
    const float* w_noise = (const float*)d_in[11];
    const float* b_noise = (const float*)d_in[12];
    const float* we1     = (const float*)d_in[13];
    const float* be1     = (const float*)d_in[14];
    const float* we2     = (const float*)d_in[15];
    const float* be2     = (const float*)d_in[16];
    const float* w_mlp1  = (const float*)d_in[17];
    const float* b_mlp1  = (const float*)d_in[18];
    const float* w_mlp2  = (const float*)d_in[19];
    const float* b_mlp2  = (const float*)d_in[20];
    float* d_outf = (float*)d_out;

    // ---- workspace (80 MB peak) ----
    const size_t MB = 1024 * 1024;
    char* ws = (char*)d_ws;
    // region A (0..16M): x1h/x1l -> aoh/aol -> w_mlp1T/w_mlp2T
    bf16* x1h = (bf16*)(ws);
    bf16* x1l = (bf16*)(ws + 8 * MB);
    bf16* aoh = (bf16*)(ws);
    bf16* aol = (bf16*)(ws + 8 * MB);
    bf16* w_mlp1T = (bf16*)(ws);
    bf16* w_mlp2T = (bf16*)(ws + 8 * MB);
    // region B (16..28M): wqkvh/wqkvl -> we1T/we2T/h_e
    bf16* wqkvh = (bf16*)(ws + 16 * MB);
    bf16* wqkvl = (bf16*)(ws + 22 * MB);
    bf16* we1T  = (bf16*)(ws + 16 * MB);
    bf16* we2T  = (bf16*)(ws + 18 * MB);
    bf16* h_e   = (bf16*)(ws + 20 * MB);
    // region C (28..32M): wprojh/wprojl
    bf16* wprojh = (bf16*)(ws + 28 * MB);
    bf16* wprojl = (bf16*)(ws + 30 * MB);
    // region D (32..56M): Qh/Kh -> h_mlp (32M overlay after flash)
    bf16* Qh = (bf16*)(ws + 32 * MB);
    bf16* Kh = (bf16*)(ws + 40 * MB);
    bf16* h_mlp = (bf16*)(ws + 32 * MB);
    // region E (64..80M): VtH (8M, dead after flash) -> x2b + routing buffers
    bf16*  VtH  = (bf16*)(ws + 64 * MB);
    bf16*  x2b  = (bf16*)(ws + 64 * MB);
    int*   topi = (int*)(ws + 72 * MB);
    float* topp = (float*)(ws + 72 * MB + 32768);
    int*   sel  = (int*)(ws + 72 * MB + 65536);
    float* wgt  = (float*)(ws + 72 * MB + 98304);

    // ---- phase 1: LN1-split, weight splits ----
    ln_split_kernel<<<T_TOK/4, 256, 0, stream>>>(x, ln1_g, ln1_b, x1h, x1l);
    split_pair_kernel<<<(3*DIM*DIM)/1024, 256, 0, stream>>>(w_qkv, wqkvh, wqkvl);
    split_pair_kernel<<<(DIM*DIM)/1024,   256, 0, stream>>>(w_proj, wprojh, wprojl);

    // ---- phase 2: qkv GEMM (epilogue: Q(x log2e/8)/K hi planes, V hi-only Vt) ----
    gemm_qkv<<<dim3(3*DIM/128, T_TOK/128), 256, 0, stream>>>(
        x1h, x1l, wqkvh, wqkvl, Qh, Kh, VtH);

    // ---- phase 3: flash attention (8-wave blocks, 128 q-rows; bid&31 = bh -> XCD locality) ----
    flash_attn<<<dim3(32 * (SEQ/128)), 512, 0, stream>>>(Qh, Kh, VtH, aoh, aol);

    // ---- phase 4: proj + bias + residual -> d_out (fp32 stream) ----
    gemm_proj<<<dim3(DIM/128, T_TOK/128), 256, 0, stream>>>(
        aoh, aol, wprojh, wprojl, b_proj, x, d_outf, DIM, DIM);

    // ---- phase 5: routing (fused LN2 -> x2b) + dispatch ----
    routing_kernel<<<T_TOK/4, 256, 0, stream>>>(d_outf, ln2_g, ln2_b, w_route, b_route,
                                                w_noise, b_noise, noise, topi, topp, x2b);
    dispatch_kernel<<<1, 256, 0, stream>>>(topi, topp, sel, wgt);

    // ---- phase 6: weight transposes (aoh/x1 regions dead) ----
    transpose_conv_kernel<<<dim3(MLPH/32, DIM/32, 1),    256, 0, stream>>>(w_mlp1, w_mlp1T, DIM, MLPH);
    transpose_conv_kernel<<<dim3(DIM/32, MLPH/32, 1),    256, 0, stream>>>(w_mlp2, w_mlp2T, MLPH, DIM);
    transpose_conv_kernel<<<dim3(MOEH/32, DIM/32, NEXP), 256, 0, stream>>>(we1, we1T, DIM, MOEH);
    transpose_conv_kernel<<<dim3(DIM/32, MOEH/32, NEXP), 256, 0, stream>>>(we2, we2T, MOEH, DIM);

    // ---- phase 7: dense MLP (mlp1 bf16; mlp2 fp32 += into d_out) ----
    gemm_bt<true,true,false,0><<<dim3(MLPH/128, T_TOK/128), 256, 0, stream>>>(
        x2b, w_mlp1T, b_mlp1, h_mlp, nullptr, nullptr, nullptr, T_TOK, MLPH, DIM,
        0, 0, 0, 0, 0);
    gemm_bt<true,false,false,2><<<dim3(DIM/128, T_TOK/128), 256, 0, stream>>>(
        h_mlp, w_mlp2T, b_mlp2, nullptr, d_outf, nullptr, nullptr, T_TOK, DIM, MLPH,
        0, 0, 0, 0, 0);

    // ---- phase 8: MoE experts, batched over blockIdx.z ----
    gemm_bt<true,true,true,0><<<dim3(MOEH/128, CAP/128, NEXP), 256, 0, stream>>>(
        x2b, we1T, be1, h_e, nullptr, sel, nullptr, CAP, MOEH, DIM,
        0, (long)MOEH*DIM, MOEH, CAP, (long)CAP*MOEH);
    gemm_bt<true,false,false,3><<<dim3(DIM/128, CAP/128, NEXP), 256, 0, stream>>>(
        h_e, we2T, be2, nullptr, d_outf, sel, wgt, CAP, DIM, MOEH,
        (long)CAP*MOEH, (long)DIM*MOEH, DIM, CAP, 0);
}

// Round 16
// 556.133 us; speedup vs baseline: 1.1342x; 1.0459x over previous
//
#include <hip/hip_runtime.h>
#include <hip/hip_bf16.h>
#include <math.h>

typedef __bf16 bf16;
typedef __bf16 bf16x4 __attribute__((ext_vector_type(4)));
typedef __bf16 bf16x8 __attribute__((ext_vector_type(8)));
typedef float  f32x4  __attribute__((ext_vector_type(4)));
typedef short  s16x4  __attribute__((ext_vector_type(4)));

#define T_TOK 4096
#define DIM   1024
#define NHEAD 16
#define SEQ   2048
#define NEXP  4
#define CAP   2048
#define MLPH  4096
#define MOEH  256

__device__ __forceinline__ float gelu_exact(float v) {
    return 0.5f * v * (1.f + erff(v * 0.70710678118654752f));
}

struct HL { bf16 h, l; };
__device__ __forceinline__ HL split2(float v) {
    HL r; r.h = (bf16)v; r.l = (bf16)(v - (float)r.h); return r;
}

__device__ __forceinline__ float fast_exp2(float x) {
#if __has_builtin(__builtin_amdgcn_exp2f)
    return __builtin_amdgcn_exp2f(x);
#else
    return exp2f(x);
#endif
}

// K=16 bf16 MFMA: B-fragment layout (k = l4*4+r, n = l16) matches the QK^T C-layout -> direct P feed
__device__ __forceinline__ f32x4 mfma16(bf16x4 a, bf16x4 b, f32x4 c) {
    return __builtin_amdgcn_mfma_f32_16x16x16bf16_1k(
        __builtin_bit_cast(s16x4, a), __builtin_bit_cast(s16x4, b), c, 0, 0, 0);
}

// async global->LDS, 16B per lane; LDS dest = wave-uniform base + lane*16
__device__ __forceinline__ void gload16(const bf16* gptr, bf16* lptr) {
    __builtin_amdgcn_global_load_lds(
        (const __attribute__((address_space(1))) unsigned int*)gptr,
        (__attribute__((address_space(3))) unsigned int*)lptr,
        16, 0, 0);
}

// swizzled fragment read: logical (row, 16B-chunk cc) stored at chunk cc^(row&7)
// (staging pre-swizzles the GLOBAL source chunk by r8, LDS dest stays linear -> both-sides swizzle)
__device__ __forceinline__ bf16x8 sw_frag(const bf16* arr, int row, int cc) {
    return *(const bf16x8*)&arr[row * 64 + ((cc ^ (row & 7)) * 8)];
}
// V fragment read (b64): quad q (4 keys) of row d stored at 8B slot q^(d&15)
// -> per 16-lane quarter the 16 slots are a bijection onto all 16 bank-pairs: conflict-free
__device__ __forceinline__ bf16x4 v_frag(const bf16* arr, int d, int q) {
    return *(const bf16x4*)&arr[d * 64 + ((q ^ (d & 15)) * 4)];
}

// T1: bijective XCD-aware tile remap — applied ONLY to gemm_bt/gemm_tail mlp-role (within-run
// counter proof: mlp2 FETCH 143->49 MB). qkv/proj measured FETCH +35% with it -> plain mapping.
__device__ __forceinline__ void xcd_tile(int& bx, int& by) {
    int gx = gridDim.x;
    int nwg = gx * gridDim.y;
    int flat = blockIdx.y * gx + blockIdx.x;
    int q = nwg >> 3, r = nwg & 7;
    int xcd = flat & 7, loc = flat >> 3;
    int swz = (xcd < r ? xcd * (q + 1) : r * (q + 1) + (xcd - r) * q) + loc;
    bx = swz % gx; by = swz / gx;
}

// ---------------- LN1 -> hi/lo bf16 planes: one wave per token ----------------
__global__ __launch_bounds__(256)
void ln_split_kernel(const float* __restrict__ x, const float* __restrict__ g,
                     const float* __restrict__ b, bf16* __restrict__ oh, bf16* __restrict__ ol) {
    int wave = threadIdx.x >> 6, lane = threadIdx.x & 63;
    long t = (long)blockIdx.x * 4 + wave;
    const float* xr = x + t * DIM;
    float v[16];
    #pragma unroll
    for (int i = 0; i < 16; i++) v[i] = xr[i * 64 + lane];
    float s = 0.f, s2 = 0.f;
    #pragma unroll
    for (int i = 0; i < 16; i++) { s += v[i]; s2 += v[i] * v[i]; }
    #pragma unroll
    for (int m = 1; m < 64; m <<= 1) { s += __shfl_xor(s, m); s2 += __shfl_xor(s2, m); }
    float mu  = s * (1.f / DIM);
    float var = s2 * (1.f / DIM) - mu * mu;
    float rs  = 1.f / sqrtf(var + 1e-5f);
    #pragma unroll
    for (int i = 0; i < 16; i++) {
        int d = i * 64 + lane;
        HL sp = split2((v[i] - mu) * rs * g[d] + b[d]);
        oh[t * DIM + d] = sp.h; ol[t * DIM + d] = sp.l;
    }
}

// ---------------- elementwise fp32 -> hi/lo planes ----------------
__global__ __launch_bounds__(256)
void split_pair_kernel(const float* __restrict__ in, bf16* __restrict__ h, bf16* __restrict__ l) {
    long i0 = ((long)blockIdx.x * 256 + threadIdx.x) * 4;
    f32x4 v = *(const f32x4*)&in[i0];
    bf16x4 vh, vl;
    #pragma unroll
    for (int j = 0; j < 4; j++) { HL sp = split2(v[j]); vh[j] = sp.h; vl[j] = sp.l; }
    *(bf16x4*)&h[i0] = vh; *(bf16x4*)&l[i0] = vl;
}

// ---------------- transpose fp32 -> bf16 (32x32 tiles, batched in z) ----------------
__global__ __launch_bounds__(256)
void transpose_conv_kernel(const float* __restrict__ in, bf16* __restrict__ out, int R, int C) {
    __shared__ bf16 tile[32][33];
    long bo = (long)blockIdx.z * R * C;
    in += bo; out += bo;
    int c0 = blockIdx.x * 32, r0 = blockIdx.y * 32;
    int tx = threadIdx.x & 31, ty = threadIdx.x >> 5;
    #pragma unroll
    for (int i = 0; i < 32; i += 8)
        tile[ty + i][tx] = (bf16)in[(long)(r0 + ty + i) * C + c0 + tx];
    __syncthreads();
    #pragma unroll
    for (int i = 0; i < 32; i += 8)
        out[(long)(c0 + ty + i) * R + r0 + tx] = tile[tx][ty + i];
}

// ---------------- qkv split GEMM: glds staging (T2-swizzled); epilogue -> Q/K hi planes + hi-only Vt ----------------
// Q pre-scale folds log2(e): softmax downstream runs in exp2 domain.
// Attention path runs bf16-hi only (Q_lo/K_lo/V_lo dropped; each adds ~2^-9 rel err, >=10x under
// the 0.03125 absmax which is MLP-dominated).
// V stored transposed VtH[bh][d][s] with odd-d quad swap (s^4) so flash's conflict-free
// v_frag layout (quad q of row d at slot q^(d&15)) stages with linear global_load_lds.
__global__ __launch_bounds__(256)
void gemm_qkv(const bf16* __restrict__ Ah_g, const bf16* __restrict__ Al_g,
              const bf16* __restrict__ Bh_g, const bf16* __restrict__ Bl_g,
              bf16* __restrict__ Qh_g, bf16* __restrict__ Kh_g,
              bf16* __restrict__ VtH) {
    const int K = DIM;
    __shared__ alignas(16) bf16 Ah[8192], Al[8192], Bh[8192], Bl[8192];
    int tid = threadIdx.x;
    int wave = tid >> 6, lane = tid & 63;
    int l16 = lane & 15, l4 = lane >> 4;
    int wr = (wave >> 1) * 64, wc = (wave & 1) * 64;
    int row0 = blockIdx.y * 128, col0 = blockIdx.x * 128;
    int r8s = lane >> 3;                      // row within 8-row staging group (== row&7)
    int colb = ((lane & 7) ^ r8s) * 8;        // pre-swizzled global 16B chunk
    f32x4 acc[4][4] = {};
    for (int k0 = 0; k0 < K; k0 += 64) {
        #pragma unroll
        for (int p = 0; p < 4; p++) {
            int rl = p * 32 + wave * 8 + r8s;
            int lb = p * 2048 + wave * 512;
            gload16(&Ah_g[(long)(row0 + rl) * K + k0 + colb], &Ah[lb]);
            gload16(&Al_g[(long)(row0 + rl) * K + k0 + colb], &Al[lb]);
            gload16(&Bh_g[(long)(col0 + rl) * K + k0 + colb], &Bh[lb]);
            gload16(&Bl_g[(long)(col0 + rl) * K + k0 + colb], &Bl[lb]);
        }
        __syncthreads();
        #pragma unroll
        for (int ks = 0; ks < 2; ks++) {
            bf16x8 ah[4], al[4], bh[4], bl[4];
            #pragma unroll
            for (int i = 0; i < 4; i++) {
                ah[i] = sw_frag(Ah, wr + i*16 + l16, ks*4 + l4);
                al[i] = sw_frag(Al, wr + i*16 + l16, ks*4 + l4);
            }
            #pragma unroll
            for (int j = 0; j < 4; j++) {
                bh[j] = sw_frag(Bh, wc + j*16 + l16, ks*4 + l4);
                bl[j] = sw_frag(Bl, wc + j*16 + l16, ks*4 + l4);
            }
            #pragma unroll
            for (int i = 0; i < 4; i++)
                #pragma unroll
                for (int j = 0; j < 4; j++) {
                    acc[i][j] = __builtin_amdgcn_mfma_f32_16x16x32_bf16(ah[i], bh[j], acc[i][j], 0, 0, 0);
                    acc[i][j] = __builtin_amdgcn_mfma_f32_16x16x32_bf16(ah[i], bl[j], acc[i][j], 0, 0, 0);
                    acc[i][j] = __builtin_amdgcn_mfma_f32_16x16x32_bf16(al[i], bh[j], acc[i][j], 0, 0, 0);
                }
        }
        __syncthreads();
    }
    if (col0 < 2048) {   // Q/K columns -> hi planes [bh][s][64]; Q pre-scaled by log2(e)/8 (exp2-domain)
        bool isQ = (col0 < 1024);
        bf16* oh = isQ ? Qh_g : Kh_g;
        float qscale = isQ ? 0.18033688011112043f : 1.0f;
        #pragma unroll
        for (int i = 0; i < 4; i++)
            #pragma unroll
            for (int r = 0; r < 4; r++) {
                int t = row0 + wr + i * 16 + l4 * 4 + r;
                int bq = t >> 11, s = t & 2047;
                #pragma unroll
                for (int j = 0; j < 4; j++) {
                    int col = (col0 + wc + j * 16 + l16) & 1023;
                    int hh = col >> 6, dl = col & 63;
                    long o = ((long)(bq * NHEAD + hh) * SEQ + s) * 64 + dl;
                    oh[o] = (bf16)(acc[i][j][r] * qscale);
                }
            }
    } else {             // V columns -> hi-only transposed VtH[bh][d][s], r-packed b64 stores; odd-d quad swap
        #pragma unroll
        for (int i = 0; i < 4; i++) {
            int s0 = row0 + wr + i * 16 + l4 * 4;
            int b = s0 >> 11, sl = s0 & 2047;
            #pragma unroll
            for (int j = 0; j < 4; j++) {
                int d = col0 - 2048 + wc + j * 16 + l16;
                int h = d >> 6, dl = d & 63;
                long base = ((long)(b * NHEAD + h) * 64 + dl) * SEQ + (sl ^ ((dl & 1) << 2));
                bf16x4 vh;
                #pragma unroll
                for (int r = 0; r < 4; r++) vh[r] = (bf16)acc[i][j][r];
                *(bf16x4*)&VtH[base] = vh;
            }
        }
    }
}

// ---------------- flash attention: 8-wave blocks (128 q-rows), double-buffered K/V, counted vmcnt ----------------
// bf16-hi attention: S = K_hi x Q_hi (8 MFMAs/tile); PV = V_hi x P via K=16 MFMA with P fed
// straight from the QK accumulator (B-fragment k=l4*4+r == st layout; no shuffle, no LDS).
__global__ __launch_bounds__(512, 4)
void flash_attn(const bf16* __restrict__ Qh_g,
                const bf16* __restrict__ Kh_g,
                const bf16* __restrict__ VtH_g,
                bf16* __restrict__ aoh, bf16* __restrict__ aol) {
    __shared__ alignas(16) bf16 KhS[2][4096], VhS[2][4096];
    int tid = threadIdx.x;
    int wave = tid >> 6, lane = tid & 63;   // wave in [0,8)
    int l16 = lane & 15, l4 = lane >> 4;
    int bid = blockIdx.x;
    int bh = bid & 31;            // same-bh blocks share XCD (bid%8 == bh%8) -> K/V stay in that L2
    int b = bh >> 4, h = bh & 15;
    int q0 = (bid >> 5) * 128;

    // Q_hi fragments (pre-scaled by log2(e)/8 at producer) straight into registers
    bf16x8 qfh[2];
    {
        const bf16* qh = Qh_g + ((long)bh * SEQ + q0 + wave * 16 + l16) * 64;
        #pragma unroll
        for (int ks = 0; ks < 2; ks++)
            qfh[ks] = *(const bf16x8*)&qh[ks * 32 + l4 * 8];
    }
    int r8 = lane >> 3;
    int c8 = lane & 7;
    const bf16* kh_g = Kh_g + (long)bh * SEQ * 64;
    const bf16* vh_g = VtH_g + (long)bh * 64 * SEQ;

    float m_s = -1e30f, l_s = 0.f;
    f32x4 accO[4] = {};

    // stage one 64-key tile (2 gload16 per wave; wave w owns rows w*8..w*8+7) into buffer bsel
    auto stage = [&](int c0, int bsel) {
        int R0 = wave * 8;
        int row = R0 + r8;
        int ksw = (c8 ^ r8) * 8;                               // K: 16B chunk ^ (row&7)
        int vsw = (c8 ^ ((wave * 4 + (r8 >> 1)) & 7)) * 8;     // V: chunk ^ ((d>>1)&7); bit0 via global quad swap
        gload16(&kh_g[(long)(c0 + row) * 64 + ksw], &KhS[bsel][R0 * 64]);
        gload16(&vh_g[(long)row * SEQ + c0 + vsw], &VhS[bsel][R0 * 64]);
    };

    // one tile's compute on the given buffers
    auto compute = [&](const bf16* KhT, const bf16* VhT) {
        // S^T[key][q] = K_hi Q_hi^T for keys [0,64), q-cols [wave*16, +16)  (exp2 domain)
        f32x4 st[4] = {};
        __builtin_amdgcn_s_setprio(1);
        #pragma unroll
        for (int ks = 0; ks < 2; ks++) {
            #pragma unroll
            for (int i = 0; i < 4; i++) {
                bf16x8 akh = sw_frag(KhT, i * 16 + l16, ks * 4 + l4);
                st[i] = __builtin_amdgcn_mfma_f32_16x16x32_bf16(akh, qfh[ks], st[i], 0, 0, 0);
            }
        }
        __builtin_amdgcn_s_setprio(0);
        // online softmax over this lane's q-column (16 keys in-reg + 2 shuffles over l4)
        float mx = st[0][0];
        #pragma unroll
        for (int i = 0; i < 4; i++)
            #pragma unroll
            for (int r = 0; r < 4; r++) mx = fmaxf(mx, st[i][r]);
        mx = fmaxf(mx, __shfl_xor(mx, 16));
        mx = fmaxf(mx, __shfl_xor(mx, 32));
        // defer-max: keep old m while tile max hasn't grown by >8 (exp2 domain -> P <= 256)
        if (!__all(mx <= m_s + 8.f)) {
            float mnew = fmaxf(m_s, mx);
            float alpha = fast_exp2(m_s - mnew);
            l_s *= alpha;
            #pragma unroll
            for (int i = 0; i < 4; i++)
                #pragma unroll
                for (int r = 0; r < 4; r++) accO[i][r] *= alpha;
            m_s = mnew;
        }
        float psum = 0.f;
        bf16x4 ph[4];
        #pragma unroll
        for (int kb = 0; kb < 4; kb++)
            #pragma unroll
            for (int r = 0; r < 4; r++) {
                float pv = fast_exp2(st[kb][r] - m_s);
                psum += pv;
                ph[kb][r] = (bf16)pv;
            }
        psum += __shfl_xor(psum, 16);
        psum += __shfl_xor(psum, 32);
        l_s += psum;
        // O^T += Vt @ P^T : K=16 MFMA, B-fragment (k=l4*4+r, n=l16) == st register layout -> direct feed
        __builtin_amdgcn_s_setprio(1);
        #pragma unroll
        for (int kb = 0; kb < 4; kb++) {
            #pragma unroll
            for (int i = 0; i < 4; i++) {
                bf16x4 avh = v_frag(VhT, i * 16 + l16, kb * 4 + l4);
                accO[i] = mfma16(avh, ph[kb], accO[i]);
            }
        }
        __builtin_amdgcn_s_setprio(0);
    };

    const int NT = SEQ / 64;   // 32, even
    stage(0, 0);
    #pragma unroll 1
    for (int t = 0; t < NT; t += 2) {
        stage((t + 1) * 64, 1);
        asm volatile("s_waitcnt vmcnt(2)" ::: "memory");
        __builtin_amdgcn_sched_barrier(0);
        __builtin_amdgcn_s_barrier();
        compute(KhS[0], VhS[0]);
        asm volatile("" ::: "memory");
        __builtin_amdgcn_s_barrier();
        if (t + 2 < NT) {
            stage((t + 2) * 64, 0);
            asm volatile("s_waitcnt vmcnt(2)" ::: "memory");
        } else {
            asm volatile("s_waitcnt vmcnt(0)" ::: "memory");
        }
        __builtin_amdgcn_sched_barrier(0);
        __builtin_amdgcn_s_barrier();
        compute(KhS[1], VhS[1]);
        asm volatile("" ::: "memory");
        __builtin_amdgcn_s_barrier();
    }

    // epilogue: lane owns q = q0 + wave*16 + l16; d = i*16 + l4*4 + r -> b64 packed
    float inv = 1.f / l_s;
    int q = q0 + wave * 16 + l16;
    #pragma unroll
    for (int i = 0; i < 4; i++) {
        bf16x4 oh4, ol4;
        #pragma unroll
        for (int r = 0; r < 4; r++) { HL sp = split2(accO[i][r] * inv); oh4[r] = sp.h; ol4[r] = sp.l; }
        long o = ((long)(b * SEQ + q)) * DIM + h * 64 + i * 16 + l4 * 4;
        *(bf16x4*)&aoh[o] = oh4;
        *(bf16x4*)&aol[o] = ol4;
    }
}

// ---------------- proj split GEMM (glds, T2-swizzled): C = A@Bt^T + bias + residual -> fp32 ----------------
__global__ __launch_bounds__(256)
void gemm_proj(const bf16* __restrict__ Ah_g, const bf16* __restrict__ Al_g,
               const bf16* __restrict__ Bh_g, const bf16* __restrict__ Bl_g,
               const float* __restrict__ bias, const float* __restrict__ res,
               float* __restrict__ C, int N, int K) {
    __shared__ alignas(16) bf16 Ah[8192], Al[8192], Bh[8192], Bl[8192];
    int tid = threadIdx.x;
    int wave = tid >> 6, lane = tid & 63;
    int l16 = lane & 15, l4 = lane >> 4;
    int wr = (wave >> 1) * 64, wc = (wave & 1) * 64;
    int row0 = blockIdx.y * 128, col0 = blockIdx.x * 128;
    int r8s = lane >> 3;
    int colb = ((lane & 7) ^ r8s) * 8;        // pre-swizzled global 16B chunk
    f32x4 acc[4][4] = {};
    for (int k0 = 0; k0 < K; k0 += 64) {
        #pragma unroll
        for (int p = 0; p < 4; p++) {
            int rl = p * 32 + wave * 8 + r8s;
            int lb = p * 2048 + wave * 512;
            gload16(&Ah_g[(long)(row0 + rl) * K + k0 + colb], &Ah[lb]);
            gload16(&Al_g[(long)(row0 + rl) * K + k0 + colb], &Al[lb]);
            gload16(&Bh_g[(long)(col0 + rl) * K + k0 + colb], &Bh[lb]);
            gload16(&Bl_g[(long)(col0 + rl) * K + k0 + colb], &Bl[lb]);
        }
        __syncthreads();
        #pragma unroll
        for (int ks = 0; ks < 2; ks++) {
            bf16x8 ah[4], al[4], bh[4], bl[4];
            #pragma unroll
            for (int i = 0; i < 4; i++) {
                ah[i] = sw_frag(Ah, wr + i*16 + l16, ks*4 + l4);
                al[i] = sw_frag(Al, wr + i*16 + l16, ks*4 + l4);
            }
            #pragma unroll
            for (int j = 0; j < 4; j++) {
                bh[j] = sw_frag(Bh, wc + j*16 + l16, ks*4 + l4);
                bl[j] = sw_frag(Bl, wc + j*16 + l16, ks*4 + l4);
            }
            #pragma unroll
            for (int i = 0; i < 4; i++)
                #pragma unroll
                for (int j = 0; j < 4; j++) {
                    acc[i][j] = __builtin_amdgcn_mfma_f32_16x16x32_bf16(ah[i], bh[j], acc[i][j], 0, 0, 0);
                    acc[i][j] = __builtin_amdgcn_mfma_f32_16x16x32_bf16(ah[i], bl[j], acc[i][j], 0, 0, 0);
                    acc[i][j] = __builtin_amdgcn_mfma_f32_16x16x32_bf16(al[i], bh[j], acc[i][j], 0, 0, 0);
                }
        }
        __syncthreads();
    }
    #pragma unroll
    for (int i = 0; i < 4; i++)
        #pragma unroll
        for (int r = 0; r < 4; r++) {
            int grow = row0 + wr + i * 16 + l4 * 4 + r;
            #pragma unroll
            for (int j = 0; j < 4; j++) {
                int gcol = col0 + wc + j * 16 + l16;
                long o = (long)grow * N + gcol;
                C[o] = acc[i][j][r] + bias[gcol] + res[o];
            }
        }
}

// ---------------- plain bf16 GEMM (glds staging, T2-swizzled, T1-remapped), expert-batched via blockIdx.z ----------------
// OUT_MODE 0: bf16 store; 2: fp32 += v; 3: atomicAdd(Cf[rowmap[row]*N+col], roww[row]*v)
template<bool BIAS, bool GELU, bool GATHER, int OUT_MODE>
__global__ __launch_bounds__(256)
void gemm_bt(const bf16* __restrict__ A, const bf16* __restrict__ Bt,
             const float* __restrict__ bias,
             bf16* __restrict__ Cbf, float* __restrict__ Cf,
             const int* __restrict__ rowmap, const float* __restrict__ roww,
             int M, int N, int K,
             long eA, long eB, long ebias, long eMap, long eC) {
    int ez = blockIdx.z;
    A += (long)ez * eA; Bt += (long)ez * eB;
    if (BIAS) bias += (long)ez * ebias;
    if (GATHER || OUT_MODE == 3) rowmap += (long)ez * eMap;
    if (OUT_MODE == 3) roww += (long)ez * eMap;
    if (OUT_MODE == 0) Cbf += (long)ez * eC;

    __shared__ alignas(16) bf16 As[8192];
    __shared__ alignas(16) bf16 Bs[8192];
    int tid = threadIdx.x;
    int wave = tid >> 6, lane = tid & 63;
    int l16 = lane & 15, l4 = lane >> 4;
    int wr = (wave >> 1) * 64, wc = (wave & 1) * 64;
    int bx, by; xcd_tile(bx, by);
    int row0 = by * 128, col0 = bx * 128;
    int r8s = lane >> 3;
    int colb = ((lane & 7) ^ r8s) * 8;        // pre-swizzled global 16B chunk

    long arow[4];
    #pragma unroll
    for (int p = 0; p < 4; p++) {
        long gr = row0 + p * 32 + wave * 8 + r8s;
        if (GATHER) gr = rowmap[gr];
        arow[p] = gr;
    }
    f32x4 acc[4][4] = {};
    for (int k0 = 0; k0 < K; k0 += 64) {
        #pragma unroll
        for (int p = 0; p < 4; p++) {
            int rl = p * 32 + wave * 8 + r8s;
            int lb = p * 2048 + wave * 512;
            gload16(&A[arow[p] * K + k0 + colb], &As[lb]);
            gload16(&Bt[(long)(col0 + rl) * K + k0 + colb], &Bs[lb]);
        }
        __syncthreads();
        #pragma unroll
        for (int ks = 0; ks < 2; ks++) {
            bf16x8 af[4], bfr[4];
            #pragma unroll
            for (int i = 0; i < 4; i++) af[i]  = sw_frag(As, wr + i*16 + l16, ks*4 + l4);
            #pragma unroll
            for (int j = 0; j < 4; j++) bfr[j] = sw_frag(Bs, wc + j*16 + l16, ks*4 + l4);
            #pragma unroll
            for (int i = 0; i < 4; i++)
                #pragma unroll
                for (int j = 0; j < 4; j++)
                    acc[i][j] = __builtin_amdgcn_mfma_f32_16x16x32_bf16(af[i], bfr[j], acc[i][j], 0, 0, 0);
        }
        __syncthreads();
    }
    #pragma unroll
    for (int i = 0; i < 4; i++)
        #pragma unroll
        for (int r = 0; r < 4; r++) {
            int grow = row0 + wr + i * 16 + l4 * 4 + r;
            int st = 0; float sw = 0.f;
            if (OUT_MODE == 3) { st = rowmap[grow]; sw = roww[grow]; }
            #pragma unroll
            for (int j = 0; j < 4; j++) {
                int gcol = col0 + wc + j * 16 + l16;
                float v = acc[i][j][r];
                if (BIAS) v += bias[gcol];
                if (GELU) v = gelu_exact(v);
                if (OUT_MODE == 0) {
                    Cbf[(long)grow * N + gcol] = (bf16)v;
                } else if (OUT_MODE == 2) {
                    long o = (long)grow * N + gcol;
                    Cf[o] += v;
                } else {
                    atomicAdd(&Cf[(long)st * N + gcol], sw * v);
                }
            }
        }
}

// ---------------- fused tail GEMM: mlp2 (atomic +=) and moe2 (scatter-atomic) in ONE launch ----------------
// The two GEMMs are dependency-independent and both accumulate into d_out. Merging gives
// 768 blocks = 3 blocks/CU so moe2's waves hide mlp2's 1-block/CU load latency (the starvation
// that resisted split-K r7 and small tiles r14). Both roles use the proven 128^2/BK=64 body.
// mlp2's += becomes atomicAdd (same addition set; fp32 order wiggle ~ulp, absmax headroom >>).
__global__ __launch_bounds__(256)
void gemm_tail(const bf16* __restrict__ A1, const bf16* __restrict__ B1, const float* __restrict__ bias1,
               const bf16* __restrict__ A2, const bf16* __restrict__ B2, const float* __restrict__ bias2,
               const int* __restrict__ sel, const float* __restrict__ wgt,
               float* __restrict__ Cf) {
    __shared__ alignas(16) bf16 As[8192];
    __shared__ alignas(16) bf16 Bs[8192];
    int tid = threadIdx.x;
    int wave = tid >> 6, lane = tid & 63;
    int l16 = lane & 15, l4 = lane >> 4;
    int wr = (wave >> 1) * 64, wc = (wave & 1) * 64;
    int r8s = lane >> 3;
    int colb = ((lane & 7) ^ r8s) * 8;        // pre-swizzled global 16B chunk

    const bf16 *A, *Bt;
    const float* bias;
    const int* rowmap = nullptr;
    const float* roww = nullptr;
    int row0, col0, K;
    bool isMoe;
    int bid = blockIdx.x;
    if (bid < 256) {
        // mlp2: C[4096,1024] (+=) h_mlp[4096,4096] @ w_mlp2T^T + b_mlp2
        isMoe = false;
        int xcd = bid & 7, loc = bid >> 3;    // T1 remap (nwg=256, gx=8; 256%8==0 -> bijective)
        int swz = xcd * 32 + loc;
        int bx = swz & 7, by = swz >> 3;
        row0 = by * 128; col0 = bx * 128;
        A = A1; Bt = B1; bias = bias1; K = MLPH;
    } else {
        // moe2 expert ez: scatter-atomic into C via sel/wgt; 128 blocks per expert (8 x 16)
        isMoe = true;
        int mid = bid - 256;
        int ez = mid >> 7;
        int lid = mid & 127;
        int bx = lid & 7, by = lid >> 3;
        row0 = by * 128; col0 = bx * 128;
        A = A2 + (long)ez * CAP * MOEH;
        Bt = B2 + (long)ez * DIM * MOEH;
        bias = bias2 + (long)ez * DIM;
        rowmap = sel + ez * CAP;
        roww = wgt + ez * CAP;
        K = MOEH;
    }

    f32x4 acc[4][4] = {};
    for (int k0 = 0; k0 < K; k0 += 64) {
        #pragma unroll
        for (int p = 0; p < 4; p++) {
            int rl = p * 32 + wave * 8 + r8s;
            int lb = p * 2048 + wave * 512;
            gload16(&A[(long)(row0 + rl) * K + k0 + colb], &As[lb]);
            gload16(&Bt[(long)(col0 + rl) * K + k0 + colb], &Bs[lb]);
        }
        __syncthreads();
        #pragma unroll
        for (int ks = 0; ks < 2; ks++) {
            bf16x8 af[4], bfr[4];
            #pragma unroll
            for (int i = 0; i < 4; i++) af[i]  = sw_frag(As, wr + i*16 + l16, ks*4 + l4);
            #pragma unroll
            for (int j = 0; j < 4; j++) bfr[j] = sw_frag(Bs, wc + j*16 + l16, ks*4 + l4);
            #pragma unroll
            for (int i = 0; i < 4; i++)
                #pragma unroll
                for (int j = 0; j < 4; j++)
                    acc[i][j] = __builtin_amdgcn_mfma_f32_16x16x32_bf16(af[i], bfr[j], acc[i][j], 0, 0, 0);
        }
        __syncthreads();
    }
    #pragma unroll
    for (int i = 0; i < 4; i++)
        #pragma unroll
        for (int r = 0; r < 4; r++) {
            int grow = row0 + wr + i * 16 + l4 * 4 + r;
            int st = 0; float sw = 0.f;
            if (isMoe) { st = rowmap[grow]; sw = roww[grow]; }
            #pragma unroll
            for (int j = 0; j < 4; j++) {
                int gcol = col0 + wc + j * 16 + l16;
                float v = acc[i][j][r] + bias[gcol];
                if (isMoe) atomicAdd(&Cf[(long)st * DIM + gcol], sw * v);
                else       atomicAdd(&Cf[(long)grow * DIM + gcol], v);
            }
        }
}

// ---------------- routing (pure fp32, LN inline) + fused x2b store: one wave per token ----------------
__global__ __launch_bounds__(256)
void routing_kernel(const float* __restrict__ xres, const float* __restrict__ g,
                    const float* __restrict__ b, const float* __restrict__ w_route,
                    const float* __restrict__ b_route, const float* __restrict__ w_noise,
                    const float* __restrict__ b_noise, const float* __restrict__ noise,
                    int* __restrict__ topi, float* __restrict__ topp,
                    bf16* __restrict__ x2b) {
    int wave = threadIdx.x >> 6, lane = threadIdx.x & 63;
    long t = (long)blockIdx.x * 4 + wave;
    const float* xr = xres + t * DIM;
    float v[16];
    #pragma unroll
    for (int i = 0; i < 16; i++) v[i] = xr[i * 64 + lane];
    float s = 0.f, s2 = 0.f;
    #pragma unroll
    for (int i = 0; i < 16; i++) { s += v[i]; s2 += v[i] * v[i]; }
    #pragma unroll
    for (int m = 1; m < 64; m <<= 1) { s += __shfl_xor(s, m); s2 += __shfl_xor(s2, m); }
    float mu  = s * (1.f / DIM);
    float var = s2 * (1.f / DIM) - mu * mu;
    float rs  = 1.f / sqrtf(var + 1e-5f);
    float accr[4] = {0.f,0.f,0.f,0.f}, accn[4] = {0.f,0.f,0.f,0.f};
    #pragma unroll
    for (int i = 0; i < 16; i++) {
        int d = i * 64 + lane;
        float n = (v[i] - mu) * rs * g[d] + b[d];
        x2b[t * DIM + d] = (bf16)n;               // fused LN2 output
        #pragma unroll
        for (int e = 0; e < 4; e++) {
            accr[e] += n * w_route[d * 4 + e];
            accn[e] += n * w_noise[d * 4 + e];
        }
    }
    #pragma unroll
    for (int e = 0; e < 4; e++)
        #pragma unroll
        for (int m = 1; m < 64; m <<= 1) {
            accr[e] += __shfl_xor(accr[e], m);
            accn[e] += __shfl_xor(accn[e], m);
        }
    if (lane == 0) {
        float nz[4];
        #pragma unroll
        for (int e = 0; e < 4; e++) {
            float logit = accr[e] + b_route[e];
            float si = accn[e] + b_noise[e];
            float sp = si > 0.f ? si + log1pf(expf(-si)) : log1pf(expf(si));
            nz[e] = logit + noise[t * 4 + e] * sp;
        }
        int i1 = 0;
        #pragma unroll
        for (int e = 1; e < 4; e++) if (nz[e] > nz[i1]) i1 = e;
        int i2 = -1; float v2 = -1e30f;
        #pragma unroll
        for (int e = 0; e < 4; e++) if (e != i1 && nz[e] > v2) { v2 = nz[e]; i2 = e; }
        float ex = expf(v2 - nz[i1]);
        topi[t * 2]     = i1; topi[t * 2 + 1] = i2;
        topp[t * 2]     = 1.f / (1.f + ex);
        topp[t * 2 + 1] = ex / (1.f + ex);
    }
}

// ---------------- dispatch: per-expert ordered token lists (wave e = expert e) ----------------
__global__ __launch_bounds__(256)
void dispatch_kernel(const int* __restrict__ topi, const float* __restrict__ topp,
                     int* __restrict__ sel, float* __restrict__ wgt) {
    int e = threadIdx.x >> 6, lane = threadIdx.x & 63;
    int cnt = 0;
    for (int c = 0; c < T_TOK; c += 64) {
        int t = c + lane;
        int i0 = topi[t * 2], i1 = topi[t * 2 + 1];
        bool m = (i0 == e) || (i1 == e);
        unsigned long long bal = __ballot(m);
        int pos = cnt + __popcll(bal & ((1ull << lane) - 1ull));
        if (m && pos < CAP) {
            sel[e * CAP + pos] = t;
            wgt[e * CAP + pos] = (i0 == e) ? topp[t * 2] : topp[t * 2 + 1];
        }
        cnt += (int)__popcll(bal);
    }
    if (cnt > CAP) cnt = CAP;
    for (int pos = cnt + lane; pos < CAP; pos += 64) {
        sel[e * CAP + pos] = 0;
        wgt[e * CAP + pos] = 0.f;
    }
}

extern "C" void kernel_launch(void* const* d_in, const int* in_sizes, int n_in,
                              void* d_out, int out_size, void* d_ws, size_t ws_size,
                              hipStream_t stream) {
    (void)in_sizes; (void)n_in; (void)out_size; (void)ws_size;
    const float* x       = (const float*)d_in[0];
    const float* noise   = (const float*)d_in[1];
    const float* ln1_g   = (const float*)d_in[2];
    const float* ln1_b   = (const float*)d_in[3];
    const float* ln2_g   = (const float*)d_in[4];
    const float* ln2_b   = (const float*)d_in[5];
    const float* w_qkv   = (const float*)d_in[6];
    const float* w_proj  = (const float*)d_in[7];
    const float* b_proj  = (const float*)d_in[8];
    const float* w_route = (const float*)d_in[9];
    const float* b_route = (const float*)d_in[10];
    const float* w_noise = (const float*)d_in[11];
    const float* b_noise = (const float*)d_in[12];
    const float* we1     = (const float*)d_in[13];
    const float* be1     = (const float*)d_in[14];
    const float* we2     = (const float*)d_in[15];
    const float* be2     = (const float*)d_in[16];
    const float* w_mlp1  = (const float*)d_in[17];
    const float* b_mlp1  = (const float*)d_in[18];
    const float* w_mlp2  = (const float*)d_in[19];
    const float* b_mlp2  = (const float*)d_in[20];
    float* d_outf = (float*)d_out;

    // ---- workspace (80 MB peak) ----
    const size_t MB = 1024 * 1024;
    char* ws = (char*)d_ws;
    // region A (0..16M): x1h/x1l -> aoh/aol -> w_mlp1T/w_mlp2T
    bf16* x1h = (bf16*)(ws);
    bf16* x1l = (bf16*)(ws + 8 * MB);
    bf16* aoh = (bf16*)(ws);
    bf16* aol = (bf16*)(ws + 8 * MB);
    bf16* w_mlp1T = (bf16*)(ws);
    bf16* w_mlp2T = (bf16*)(ws + 8 * MB);
    // region B (16..28M): wqkvh/wqkvl -> we1T/we2T/h_e
    bf16* wqkvh = (bf16*)(ws + 16 * MB);
    bf16* wqkvl = (bf16*)(ws + 22 * MB);
    bf16* we1T  = (bf16*)(ws + 16 * MB);
    bf16* we2T  = (bf16*)(ws + 18 * MB);
    bf16* h_e   = (bf16*)(ws + 20 * MB);
    // region C (28..32M): wprojh/wprojl
    bf16* wprojh = (bf16*)(ws + 28 * MB);
    bf16* wprojl = (bf16*)(ws + 30 * MB);
    // region D (32..56M): Qh/Kh -> h_mlp (32M overlay after flash)
    bf16* Qh = (bf16*)(ws + 32 * MB);
    bf16* Kh = (bf16*)(ws + 40 * MB);
    bf16* h_mlp = (bf16*)(ws + 32 * MB);
    // region E (64..80M): VtH (8M, dead after flash) -> x2b + routing buffers
    bf16*  VtH  = (bf16*)(ws + 64 * MB);
    bf16*  x2b  = (bf16*)(ws + 64 * MB);
    int*   topi = (int*)(ws + 72 * MB);
    float* topp = (float*)(ws + 72 * MB + 32768);
    int*   sel  = (int*)(ws + 72 * MB + 65536);
    float* wgt  = (float*)(ws + 72 * MB + 98304);

    // ---- phase 1: LN1-split, weight splits ----
    ln_split_kernel<<<T_TOK/4, 256, 0, stream>>>(x, ln1_g, ln1_b, x1h, x1l);
    split_pair_kernel<<<(3*DIM*DIM)/1024, 256, 0, stream>>>(w_qkv, wqkvh, wqkvl);
    split_pair_kernel<<<(DIM*DIM)/1024,   256, 0, stream>>>(w_proj, wprojh, wprojl);

    // ---- phase 2: qkv GEMM (epilogue: Q(x log2e/8)/K hi planes, V hi-only Vt) ----
    gemm_qkv<<<dim3(3*DIM/128, T_TOK/128), 256, 0, stream>>>(
        x1h, x1l, wqkvh, wqkvl, Qh, Kh, VtH);

    // ---- phase 3: flash attention (8-wave blocks, 128 q-rows; bid&31 = bh -> XCD locality) ----
    flash_attn<<<dim3(32 * (SEQ/128)), 512, 0, stream>>>(Qh, Kh, VtH, aoh, aol);

    // ---- phase 4: proj + bias + residual -> d_out (fp32 stream) ----
    gemm_proj<<<dim3(DIM/128, T_TOK/128), 256, 0, stream>>>(
        aoh, aol, wprojh, wprojl, b_proj, x, d_outf, DIM, DIM);

    // ---- phase 5: routing (fused LN2 -> x2b) + dispatch ----
    routing_kernel<<<T_TOK/4, 256, 0, stream>>>(d_outf, ln2_g, ln2_b, w_route, b_route,
                                                w_noise, b_noise, noise, topi, topp, x2b);
    dispatch_kernel<<<1, 256, 0, stream>>>(topi, topp, sel, wgt);

    // ---- phase 6: weight transposes (aoh/x1 regions dead) ----
    transpose_conv_kernel<<<dim3(MLPH/32, DIM/32, 1),    256, 0, stream>>>(w_mlp1, w_mlp1T, DIM, MLPH);
    transpose_conv_kernel<<<dim3(DIM/32, MLPH/32, 1),    256, 0, stream>>>(w_mlp2, w_mlp2T, MLPH, DIM);
    transpose_conv_kernel<<<dim3(MOEH/32, DIM/32, NEXP), 256, 0, stream>>>(we1, we1T, DIM, MOEH);
    transpose_conv_kernel<<<dim3(DIM/32, MOEH/32, NEXP), 256, 0, stream>>>(we2, we2T, MOEH, DIM);

    // ---- phase 7: first-layer GEMMs (independent): mlp1 then moe1 ----
    gemm_bt<true,true,false,0><<<dim3(MLPH/128, T_TOK/128), 256, 0, stream>>>(
        x2b, w_mlp1T, b_mlp1, h_mlp, nullptr, nullptr, nullptr, T_TOK, MLPH, DIM,
        0, 0, 0, 0, 0);
    gemm_bt<true,true,true,0><<<dim3(MOEH/128, CAP/128, NEXP), 256, 0, stream>>>(
        x2b, we1T, be1, h_e, nullptr, sel, nullptr, CAP, MOEH, DIM,
        0, (long)MOEH*DIM, MOEH, CAP, (long)CAP*MOEH);

    // ---- phase 8: fused tail (mlp2 + moe2 in one launch, 768 blocks = 3/CU) ----
    gemm_tail<<<dim3(256 + (DIM/128)*(CAP/128)*NEXP), 256, 0, stream>>>(
        h_mlp, w_mlp2T, b_mlp2, h_e, we2T, be2, sel, wgt, d_outf);
}